// Round 1
// baseline (3809.959 us; speedup 1.0000x reference)
//
#include <hip/hip_runtime.h>
#include <math.h>

#define NB 8
#define N0 16384
#define NC 128
#define NE 98304

// ---------- helpers ----------
__device__ __forceinline__ unsigned mono_u(float f) {
  unsigned u = __float_as_uint(f);
  return (u & 0x80000000u) ? ~u : (u | 0x80000000u);
}
__device__ __forceinline__ int f2ikey(float f) {
  int i = __float_as_int(f);
  return (i >= 0) ? i : (i ^ 0x7fffffff);
}
__device__ __forceinline__ float ikey2f(int k) {
  return __int_as_float(k >= 0 ? k : (k ^ 0x7fffffff));
}
__device__ __forceinline__ int wscan_incl(int v, int lane) {
#pragma unroll
  for (int o = 1; o < 64; o <<= 1) {
    int u = __shfl_up(v, o);
    if (lane >= o) v += u;
  }
  return v;
}

// ---------- init: copy edges to ws, zero readout accumulator ----------
__global__ void k_init(const int* __restrict__ src, const int* __restrict__ dst,
                       int* __restrict__ srcw, int* __restrict__ dstw, float* __restrict__ r) {
  int i = blockIdx.x * blockDim.x + threadIdx.x;
  for (int j = i; j < NB * NE; j += gridDim.x * blockDim.x) {
    srcw[j] = src[j];
    dstw[j] = dst[j];
  }
  if (i < NB * 256) r[i] = 0.f;
}

// ---------- scatter messages: AGG[dst] += X[src], one wave per edge ----------
__global__ void k_scatter(const float* __restrict__ X, float* __restrict__ AGG,
                          const int* __restrict__ srcw, const int* __restrict__ dstw) {
  int gw = (blockIdx.x * blockDim.x + threadIdx.x) >> 6;
  int lane = threadIdx.x & 63;
  if (gw >= NB * NE) return;
  int d = dstw[gw];
  if (d < 0) return;
  int b = gw / NE;
  int s = srcw[gw];
  const float2 v = *reinterpret_cast<const float2*>(&X[((size_t)b * N0 + s) * NC + lane * 2]);
  float* o = &AGG[((size_t)b * N0 + d) * NC + lane * 2];
  atomicAdd(o, v.x);
  atomicAdd(o + 1, v.y);
}

// ---------- Xa += Xb over n rows per graph ----------
__global__ void k_add(float* __restrict__ Xa, const float* __restrict__ Xb, int n) {
  int per = n * (NC / 4);
  int tot = NB * per;
  for (int i = blockIdx.x * blockDim.x + threadIdx.x; i < tot; i += gridDim.x * blockDim.x) {
    int b = i / per, rme = i % per;
    size_t idx = (size_t)b * N0 * (NC / 4) + rme;
    float4 a = reinterpret_cast<float4*>(Xa)[idx];
    float4 v = reinterpret_cast<const float4*>(Xb)[idx];
    a.x += v.x; a.y += v.y; a.z += v.z; a.w += v.w;
    reinterpret_cast<float4*>(Xa)[idx] = a;
  }
}

// ---------- GEMM: Xout[r][c] = relu( Xin[r][:] @ W + bias ), 128x128 tile ----------
__global__ __launch_bounds__(256) void k_gemm(const float* __restrict__ Xin, float* __restrict__ Xout,
                                              const float* __restrict__ W, const float* __restrict__ bias,
                                              int n) {
  __shared__ float Xs[128 * 129];
  __shared__ float Ws[128 * 128];
  int b = blockIdx.y;
  int r0g = blockIdx.x * 128;
  int t = threadIdx.x;
  // stage W (64 KB)
#pragma unroll
  for (int l = 0; l < 16; l++) {
    int li = t + l * 256;
    reinterpret_cast<float4*>(Ws)[li] = reinterpret_cast<const float4*>(W)[li];
  }
  // stage X tile (pad row stride 129)
#pragma unroll
  for (int l = 0; l < 16; l++) {
    int li = t + l * 256;
    int row = li >> 5;
    int c4 = li & 31;
    float4 v = make_float4(0.f, 0.f, 0.f, 0.f);
    if (r0g + row < n)
      v = reinterpret_cast<const float4*>(&Xin[((size_t)b * N0 + r0g + row) * NC])[c4];
    float* dp = &Xs[row * 129 + c4 * 4];
    dp[0] = v.x; dp[1] = v.y; dp[2] = v.z; dp[3] = v.w;
  }
  __syncthreads();
  int ty = t >> 4, tx = t & 15;
  float acc[8][8];
#pragma unroll
  for (int i = 0; i < 8; i++)
#pragma unroll
    for (int j = 0; j < 8; j++) acc[i][j] = 0.f;

  for (int k = 0; k < 128; k++) {
    float a[8];
#pragma unroll
    for (int i = 0; i < 8; i++) a[i] = Xs[(ty * 8 + i) * 129 + k];
    float4 b0 = *reinterpret_cast<const float4*>(&Ws[k * 128 + tx * 8]);
    float4 b1 = *reinterpret_cast<const float4*>(&Ws[k * 128 + tx * 8 + 4]);
    float wv[8] = {b0.x, b0.y, b0.z, b0.w, b1.x, b1.y, b1.z, b1.w};
#pragma unroll
    for (int i = 0; i < 8; i++)
#pragma unroll
      for (int j = 0; j < 8; j++) acc[i][j] = fmaf(a[i], wv[j], acc[i][j]);
  }
  float bv[8];
#pragma unroll
  for (int j = 0; j < 8; j++) bv[j] = bias[tx * 8 + j];
#pragma unroll
  for (int i = 0; i < 8; i++) {
    int rg = r0g + ty * 8 + i;
    if (rg >= n) break;
    float4 o0, o1;
    o0.x = fmaxf(acc[i][0] + bv[0], 0.f);
    o0.y = fmaxf(acc[i][1] + bv[1], 0.f);
    o0.z = fmaxf(acc[i][2] + bv[2], 0.f);
    o0.w = fmaxf(acc[i][3] + bv[3], 0.f);
    o1.x = fmaxf(acc[i][4] + bv[4], 0.f);
    o1.y = fmaxf(acc[i][5] + bv[5], 0.f);
    o1.z = fmaxf(acc[i][6] + bv[6], 0.f);
    o1.w = fmaxf(acc[i][7] + bv[7], 0.f);
    float4* op = reinterpret_cast<float4*>(&Xout[((size_t)b * N0 + rg) * NC + tx * 8]);
    op[0] = o0; op[1] = o1;
  }
}

// ---------- score = tanh((x . pw)/||pw||), one wave per node ----------
__global__ void k_score(const float* __restrict__ X, const float* __restrict__ pw,
                        float* __restrict__ score, int n) {
  int lane = threadIdx.x & 63;
  int wid = threadIdx.x >> 6;
  int node = blockIdx.x * 4 + wid;
  int b = blockIdx.y;
  float2 p = *reinterpret_cast<const float2*>(&pw[lane * 2]);
  float nrm = p.x * p.x + p.y * p.y;
  float dot = 0.f;
  if (node < n) {
    float2 v = *reinterpret_cast<const float2*>(&X[((size_t)b * N0 + node) * NC + lane * 2]);
    dot = v.x * p.x + v.y * p.y;
  }
#pragma unroll
  for (int o = 32; o > 0; o >>= 1) {
    dot += __shfl_xor(dot, o);
    nrm += __shfl_xor(nrm, o);
  }
  if (node < n && lane == 0) score[b * N0 + node] = tanhf(dot / sqrtf(nrm));
}

// ---------- top-k threshold: bitonic sort 16384 u32 keys per graph ----------
__global__ __launch_bounds__(1024) void k_topk(const float* __restrict__ score,
                                               unsigned* __restrict__ vstar, int* __restrict__ quota,
                                               int n, int k) {
  __shared__ unsigned sk[16384];
  int b = blockIdx.x;
  int t = threadIdx.x;
  for (int j = t; j < 16384; j += 1024)
    sk[j] = (j < n) ? mono_u(score[b * N0 + j]) : 0u;
  __syncthreads();
  for (int size = 2; size <= 16384; size <<= 1) {
    for (int stride = size >> 1; stride > 0; stride >>= 1) {
      for (int idx = t; idx < 16384; idx += 1024) {
        int ixj = idx ^ stride;
        if (ixj > idx) {
          unsigned a = sk[idx], c = sk[ixj];
          bool up = ((idx & size) == 0);   // "up" blocks sorted descending -> final descending
          if (up ? (a < c) : (a > c)) { sk[idx] = c; sk[ixj] = a; }
        }
      }
      __syncthreads();
    }
  }
  if (t == 0) {
    unsigned vs = sk[k - 1];
    int lo = 0, hi = k - 1;
    while (lo < hi) {
      int mid = (lo + hi) >> 1;
      if (sk[mid] > vs) lo = mid + 1; else hi = mid;
    }
    vstar[b] = vs;
    quota[b] = k - lo;   // how many ties (by lowest index) get selected
  }
}

// ---------- mapping old->new (or -1), jax.lax.top_k tie semantics ----------
__global__ __launch_bounds__(1024) void k_map(const float* __restrict__ score,
                                              const unsigned* __restrict__ vstar,
                                              const int* __restrict__ quota,
                                              int* __restrict__ mp, int n) {
  __shared__ int wt[16], ws2[16];
  __shared__ int bases[2];  // [0]=ties so far, [1]=selected so far
  int b = blockIdx.x;
  int t = threadIdx.x, lane = t & 63, wid = t >> 6;
  if (t == 0) { bases[0] = 0; bases[1] = 0; }
  __syncthreads();
  unsigned vs = vstar[b];
  int q = quota[b];
  for (int base = 0; base < n; base += 1024) {
    int j = base + t;
    unsigned key = (j < n) ? mono_u(score[b * N0 + j]) : 0u;
    int gt = (j < n) && (key > vs);
    int tie = (j < n) && (key == vs);
    int tinc = wscan_incl(tie, lane);
    if (lane == 63) wt[wid] = tinc;
    __syncthreads();
    int woff = 0;
    for (int w = 0; w < wid; w++) woff += wt[w];
    int tie_excl = bases[0] + woff + tinc - tie;
    int sel = gt | (tie & ((tie_excl < q) ? 1 : 0));
    int sinc = wscan_incl(sel, lane);
    if (lane == 63) ws2[wid] = sinc;
    __syncthreads();
    int woff2 = 0;
    for (int w = 0; w < wid; w++) woff2 += ws2[w];
    if (j < n) mp[b * N0 + j] = sel ? (bases[1] + woff2 + sinc - sel) : -1;
    __syncthreads();
    if (t == 0) {
      int tt = 0, ss = 0;
      for (int w = 0; w < 16; w++) { tt += wt[w]; ss += ws2[w]; }
      bases[0] += tt; bases[1] += ss;
    }
    __syncthreads();
  }
}

// ---------- compact selected rows, scaled by score ----------
__global__ void k_compact(const float* __restrict__ Xin, float* __restrict__ Xout,
                          const int* __restrict__ mp, const float* __restrict__ score, int n) {
  int lane = threadIdx.x & 63, wid = threadIdx.x >> 6;
  int node = blockIdx.x * 4 + wid;
  int b = blockIdx.y;
  if (node >= n) return;
  int m = mp[b * N0 + node];
  if (m < 0) return;
  float val = score[b * N0 + node];
  float2 v = *reinterpret_cast<const float2*>(&Xin[((size_t)b * N0 + node) * NC + lane * 2]);
  v.x *= val; v.y *= val;
  *reinterpret_cast<float2*>(&Xout[((size_t)b * N0 + m) * NC + lane * 2]) = v;
}

// ---------- remap edges in place; dst=-1 marks invalid ----------
__global__ void k_remap(int* __restrict__ srcw, int* __restrict__ dstw, const int* __restrict__ mp) {
  int tot = NB * NE;
  for (int i = blockIdx.x * blockDim.x + threadIdx.x; i < tot; i += gridDim.x * blockDim.x) {
    int d = dstw[i];
    if (d < 0) continue;
    int b = i / NE;
    int s = srcw[i];
    int ns = mp[b * N0 + s], nd = mp[b * N0 + d];
    if (ns >= 0 && nd >= 0) { srcw[i] = ns; dstw[i] = nd; }
    else { srcw[i] = 0; dstw[i] = -1; }
  }
}

// ---------- readout buffers ----------
__global__ void k_zbuf(int* __restrict__ maxbuf, float* __restrict__ sumbuf) {
  int i = blockIdx.x * blockDim.x + threadIdx.x;
  if (i < NB * NC) { maxbuf[i] = (int)0x80000000; sumbuf[i] = 0.f; }
}

__global__ void k_readout(const float* __restrict__ X, int* __restrict__ maxbuf,
                          float* __restrict__ sumbuf, int n) {
  __shared__ float smx[128], ssm[128];
  int b = blockIdx.y;
  int nchunk = gridDim.x;
  int rows = (n + nchunk - 1) / nchunk;
  int lo = blockIdx.x * rows;
  int hi = min(lo + rows, n);
  int c = threadIdx.x & 127, h = threadIdx.x >> 7;
  float mx = -INFINITY, sm = 0.f;
  for (int r = lo + h; r < hi; r += 2) {
    float v = X[((size_t)b * N0 + r) * NC + c];
    mx = fmaxf(mx, v);
    sm += v;
  }
  if (h) { smx[c] = mx; ssm[c] = sm; }
  __syncthreads();
  if (!h) {
    mx = fmaxf(mx, smx[c]);
    sm += ssm[c];
    atomicMax(&maxbuf[b * NC + c], f2ikey(mx));
    atomicAdd(&sumbuf[b * NC + c], sm);
  }
}

__global__ void k_addro(const int* __restrict__ maxbuf, const float* __restrict__ sumbuf,
                        float* __restrict__ r, int nout) {
  int i = blockIdx.x * blockDim.x + threadIdx.x;
  if (i >= NB * NC) return;
  int b = i >> 7, c = i & 127;
  r[b * 256 + c] += ikey2f(maxbuf[i]);
  r[b * 256 + 128 + c] += sumbuf[i] / (float)nout;
}

// ---------- tiny predictor MLP ----------
__global__ __launch_bounds__(256) void k_pred(const float* __restrict__ r,
                                              const float* __restrict__ q1w, const float* __restrict__ q1b,
                                              const float* __restrict__ q2w, const float* __restrict__ q2b,
                                              const float* __restrict__ q3w, const float* __restrict__ q3b,
                                              float* __restrict__ out) {
  __shared__ float rr[256], h1[128], h2[64];
  int b = blockIdx.x, t = threadIdx.x;
  rr[t] = r[b * 256 + t];
  __syncthreads();
  if (t < 128) {
    float s = q1b[t];
    for (int j = 0; j < 256; j++) s = fmaf(rr[j], q1w[j * 128 + t], s);
    h1[t] = fmaxf(s, 0.f);
  }
  __syncthreads();
  if (t < 64) {
    float s = q2b[t];
    for (int j = 0; j < 128; j++) s = fmaf(h1[j], q2w[j * 64 + t], s);
    h2[t] = fmaxf(s, 0.f);
  }
  __syncthreads();
  if (t < 2) {
    float s = q3b[t];
    for (int j = 0; j < 64; j++) s = fmaf(h2[j], q3w[j * 2 + t], s);
    out[b * 2 + t] = s;
  }
}

// ---------- host orchestration ----------
extern "C" void kernel_launch(void* const* d_in, const int* in_sizes, int n_in,
                              void* d_out, int out_size, void* d_ws, size_t ws_size,
                              hipStream_t stream) {
  const float* x = (const float*)d_in[0];
  const int* src = (const int*)d_in[1];
  const int* dst = (const int*)d_in[2];
  const float* q1w = (const float*)d_in[23];
  const float* q1b = (const float*)d_in[24];
  const float* q2w = (const float*)d_in[25];
  const float* q2b = (const float*)d_in[26];
  const float* q3w = (const float*)d_in[27];
  const float* q3b = (const float*)d_in[28];

  char* p = (char*)d_ws;
  auto alloc = [&](size_t bytes) {
    char* q = p;
    p += (bytes + 255) & ~(size_t)255;
    return q;
  };
  float* Xa = (float*)alloc((size_t)NB * N0 * NC * 4);
  float* Xb = (float*)alloc((size_t)NB * N0 * NC * 4);
  int* srcw = (int*)alloc((size_t)NB * NE * 4);
  int* dstw = (int*)alloc((size_t)NB * NE * 4);
  float* score = (float*)alloc((size_t)NB * N0 * 4);
  int* mp = (int*)alloc((size_t)NB * N0 * 4);
  unsigned* vstar = (unsigned*)alloc(256);
  int* quota = (int*)alloc(256);
  int* maxbuf = (int*)alloc(NB * NC * 4);
  float* sumbuf = (float*)alloc(NB * NC * 4);
  float* r = (float*)alloc(NB * 256 * 4);

  hipMemcpyAsync(Xa, x, (size_t)NB * N0 * NC * 4, hipMemcpyDeviceToDevice, stream);
  k_init<<<1024, 256, 0, stream>>>(src, dst, srcw, dstw, r);

  static const int NSv[4] = {16384, 13108, 10487, 8390};
  static const int KSv[4] = {13108, 10487, 8390, 6712};
  float* cur = Xa;
  float* tmp = Xb;
  for (int i = 0; i < 4; i++) {
    int n = NSv[i], k = KSv[i];
    const float* w1 = (const float*)d_in[3 + i * 5 + 0];
    const float* b1 = (const float*)d_in[3 + i * 5 + 1];
    const float* w2 = (const float*)d_in[3 + i * 5 + 2];
    const float* b2 = (const float*)d_in[3 + i * 5 + 3];
    const float* pw = (const float*)d_in[3 + i * 5 + 4];

    hipMemsetAsync(tmp, 0, (size_t)NB * N0 * NC * 4, stream);
    k_scatter<<<NB * NE / 4, 256, 0, stream>>>(cur, tmp, srcw, dstw);
    k_add<<<2048, 256, 0, stream>>>(cur, tmp, n);

    dim3 gg((n + 127) / 128, NB);
    k_gemm<<<gg, 256, 0, stream>>>(cur, tmp, w1, b1, n);   // h = relu(h0 @ w1 + b1)
    k_gemm<<<gg, 256, 0, stream>>>(tmp, cur, w2, b2, n);   // x = relu(h @ w2 + b2)

    dim3 gs((n + 3) / 4, NB);
    k_score<<<gs, 256, 0, stream>>>(cur, pw, score, n);
    k_topk<<<NB, 1024, 0, stream>>>(score, vstar, quota, n, k);
    k_map<<<NB, 1024, 0, stream>>>(score, vstar, quota, mp, n);
    k_compact<<<gs, 256, 0, stream>>>(cur, tmp, mp, score, n);
    k_remap<<<1024, 256, 0, stream>>>(srcw, dstw, mp);

    float* t2 = cur; cur = tmp; tmp = t2;   // cur now holds pooled x [k rows]

    k_zbuf<<<(NB * NC + 255) / 256, 256, 0, stream>>>(maxbuf, sumbuf);
    dim3 gr(32, NB);
    k_readout<<<gr, 256, 0, stream>>>(cur, maxbuf, sumbuf, k);
    k_addro<<<(NB * NC + 255) / 256, 256, 0, stream>>>(maxbuf, sumbuf, r, k);
  }

  k_pred<<<NB, 256, 0, stream>>>(r, q1w, q1b, q2w, q2b, q3w, q3b, (float*)d_out);
}

// Round 2
// 1705.741 us; speedup vs baseline: 2.2336x; 2.2336x over previous
//
#include <hip/hip_runtime.h>
#include <math.h>

#define NB 8
#define N0 16384
#define NC 128
#define NE 98304

// ---------- helpers ----------
__device__ __forceinline__ unsigned mono_u(float f) {
  unsigned u = __float_as_uint(f);
  return (u & 0x80000000u) ? ~u : (u | 0x80000000u);
}
__device__ __forceinline__ int f2ikey(float f) {
  int i = __float_as_int(f);
  return (i >= 0) ? i : (i ^ 0x7fffffff);
}
__device__ __forceinline__ float ikey2f(int k) {
  return __int_as_float(k >= 0 ? k : (k ^ 0x7fffffff));
}
__device__ __forceinline__ int wscan_incl(int v, int lane) {
#pragma unroll
  for (int o = 1; o < 64; o <<= 1) {
    int u = __shfl_up(v, o);
    if (lane >= o) v += u;
  }
  return v;
}

// ---------- init: copy edges to ws, zero readout accumulator ----------
__global__ void k_init(const int* __restrict__ src, const int* __restrict__ dst,
                       int* __restrict__ srcw, int* __restrict__ dstw, float* __restrict__ r) {
  int i = blockIdx.x * blockDim.x + threadIdx.x;
  for (int j = i; j < NB * NE; j += gridDim.x * blockDim.x) {
    srcw[j] = src[j];
    dstw[j] = dst[j];
  }
  if (i < NB * 256) r[i] = 0.f;
}

// ---------- CSR build: count incoming edges per node ----------
__global__ void k_count(const int* __restrict__ dstw, int* __restrict__ cnt) {
  int tot = NB * NE;
  for (int i = blockIdx.x * blockDim.x + threadIdx.x; i < tot; i += gridDim.x * blockDim.x) {
    int d = dstw[i];
    if (d >= 0) atomicAdd(&cnt[(i / NE) * N0 + d], 1);
  }
}

// ---------- CSR build: per-graph exclusive scan over 16384 counts ----------
__global__ __launch_bounds__(1024) void k_scan(const int* __restrict__ cnt,
                                               int* __restrict__ offs, int* __restrict__ cursor) {
  __shared__ int ws[1024];
  int b = blockIdx.x, t = threadIdx.x;
  int base = b * N0 + t * 16;
  int loc[16];
  int s = 0;
#pragma unroll
  for (int j = 0; j < 16; j++) { loc[j] = cnt[base + j]; s += loc[j]; }
  ws[t] = s;
  __syncthreads();
  for (int o = 1; o < 1024; o <<= 1) {
    int v = (t >= o) ? ws[t - o] : 0;
    __syncthreads();
    ws[t] += v;
    __syncthreads();
  }
  int excl = ws[t] - s;
#pragma unroll
  for (int j = 0; j < 16; j++) {
    offs[base + j] = excl;
    cursor[base + j] = excl;
    excl += loc[j];
  }
}

// ---------- CSR build: fill edge list (src ids bucketed by dst) ----------
__global__ void k_fill(const int* __restrict__ srcw, const int* __restrict__ dstw,
                       int* __restrict__ cursor, int* __restrict__ elist) {
  int tot = NB * NE;
  for (int i = blockIdx.x * blockDim.x + threadIdx.x; i < tot; i += gridDim.x * blockDim.x) {
    int d = dstw[i];
    if (d < 0) continue;
    int b = i / NE;
    int pos = atomicAdd(&cursor[b * N0 + d], 1);
    elist[b * NE + pos] = srcw[i];
  }
}

// ---------- gather: H[node] = X[node] + sum_{src in CSR[node]} X[src] ----------
__global__ void k_gather(const float* __restrict__ X, float* __restrict__ H,
                         const int* __restrict__ offs, const int* __restrict__ cnt,
                         const int* __restrict__ elist, int n) {
  int lane = threadIdx.x & 63, wid = threadIdx.x >> 6;
  int node = blockIdx.x * 4 + wid;
  int b = blockIdx.y;
  if (node >= n) return;
  int off = offs[b * N0 + node];
  int deg = cnt[b * N0 + node];
  const float* Xb = X + (size_t)b * N0 * NC;
  float2 acc = *reinterpret_cast<const float2*>(&Xb[(size_t)node * NC + lane * 2]);
  for (int base = 0; base < deg; base += 64) {
    int m = min(64, deg - base);
    int eid = (lane < m) ? elist[b * NE + off + base + lane] : 0;
    for (int j = 0; j < m; j++) {
      int s = __shfl(eid, j);
      float2 v = *reinterpret_cast<const float2*>(&Xb[(size_t)s * NC + lane * 2]);
      acc.x += v.x;
      acc.y += v.y;
    }
  }
  *reinterpret_cast<float2*>(&H[((size_t)b * N0 + node) * NC + lane * 2]) = acc;
}

// ---------- GEMM: Xout[r][c] = relu( Xin[r][:] @ W + bias ), 128x128 tile ----------
__global__ __launch_bounds__(256) void k_gemm(const float* __restrict__ Xin, float* __restrict__ Xout,
                                              const float* __restrict__ W, const float* __restrict__ bias,
                                              int n) {
  __shared__ float Xs[128 * 129];
  __shared__ float Ws[128 * 128];
  int b = blockIdx.y;
  int r0g = blockIdx.x * 128;
  int t = threadIdx.x;
#pragma unroll
  for (int l = 0; l < 16; l++) {
    int li = t + l * 256;
    reinterpret_cast<float4*>(Ws)[li] = reinterpret_cast<const float4*>(W)[li];
  }
#pragma unroll
  for (int l = 0; l < 16; l++) {
    int li = t + l * 256;
    int row = li >> 5;
    int c4 = li & 31;
    float4 v = make_float4(0.f, 0.f, 0.f, 0.f);
    if (r0g + row < n)
      v = reinterpret_cast<const float4*>(&Xin[((size_t)b * N0 + r0g + row) * NC])[c4];
    float* dp = &Xs[row * 129 + c4 * 4];
    dp[0] = v.x; dp[1] = v.y; dp[2] = v.z; dp[3] = v.w;
  }
  __syncthreads();
  int ty = t >> 4, tx = t & 15;
  float acc[8][8];
#pragma unroll
  for (int i = 0; i < 8; i++)
#pragma unroll
    for (int j = 0; j < 8; j++) acc[i][j] = 0.f;

  for (int k = 0; k < 128; k++) {
    float a[8];
#pragma unroll
    for (int i = 0; i < 8; i++) a[i] = Xs[(ty * 8 + i) * 129 + k];
    float4 b0 = *reinterpret_cast<const float4*>(&Ws[k * 128 + tx * 8]);
    float4 b1 = *reinterpret_cast<const float4*>(&Ws[k * 128 + tx * 8 + 4]);
    float wv[8] = {b0.x, b0.y, b0.z, b0.w, b1.x, b1.y, b1.z, b1.w};
#pragma unroll
    for (int i = 0; i < 8; i++)
#pragma unroll
      for (int j = 0; j < 8; j++) acc[i][j] = fmaf(a[i], wv[j], acc[i][j]);
  }
  float bv[8];
#pragma unroll
  for (int j = 0; j < 8; j++) bv[j] = bias[tx * 8 + j];
#pragma unroll
  for (int i = 0; i < 8; i++) {
    int rg = r0g + ty * 8 + i;
    if (rg >= n) break;
    float4 o0, o1;
    o0.x = fmaxf(acc[i][0] + bv[0], 0.f);
    o0.y = fmaxf(acc[i][1] + bv[1], 0.f);
    o0.z = fmaxf(acc[i][2] + bv[2], 0.f);
    o0.w = fmaxf(acc[i][3] + bv[3], 0.f);
    o1.x = fmaxf(acc[i][4] + bv[4], 0.f);
    o1.y = fmaxf(acc[i][5] + bv[5], 0.f);
    o1.z = fmaxf(acc[i][6] + bv[6], 0.f);
    o1.w = fmaxf(acc[i][7] + bv[7], 0.f);
    float4* op = reinterpret_cast<float4*>(&Xout[((size_t)b * N0 + rg) * NC + tx * 8]);
    op[0] = o0; op[1] = o1;
  }
}

// ---------- score = tanh((x . pw)/||pw||), one wave per node ----------
__global__ void k_score(const float* __restrict__ X, const float* __restrict__ pw,
                        float* __restrict__ score, int n) {
  int lane = threadIdx.x & 63;
  int wid = threadIdx.x >> 6;
  int node = blockIdx.x * 4 + wid;
  int b = blockIdx.y;
  float2 p = *reinterpret_cast<const float2*>(&pw[lane * 2]);
  float nrm = p.x * p.x + p.y * p.y;
  float dot = 0.f;
  if (node < n) {
    float2 v = *reinterpret_cast<const float2*>(&X[((size_t)b * N0 + node) * NC + lane * 2]);
    dot = v.x * p.x + v.y * p.y;
  }
#pragma unroll
  for (int o = 32; o > 0; o >>= 1) {
    dot += __shfl_xor(dot, o);
    nrm += __shfl_xor(nrm, o);
  }
  if (node < n && lane == 0) score[b * N0 + node] = tanhf(dot / sqrtf(nrm));
}

// ---------- top-k threshold via 4-pass radix select on monotone u32 keys ----------
__global__ __launch_bounds__(1024) void k_select(const float* __restrict__ score,
                                                 unsigned* __restrict__ vstar, int* __restrict__ quota,
                                                 int n, int k) {
  __shared__ int hist[256];
  __shared__ unsigned s_pref;
  __shared__ int s_r, s_gt;
  int b = blockIdx.x, t = threadIdx.x;
  if (t == 0) { s_pref = 0u; s_r = k; s_gt = 0; }
  __syncthreads();
  for (int pass = 0; pass < 4; ++pass) {
    int shift = 24 - pass * 8;
    if (t < 256) hist[t] = 0;
    __syncthreads();
    unsigned pref = s_pref;
    unsigned pmask = (pass == 0) ? 0u : (0xFFFFFFFFu << (shift + 8));
    for (int j = t; j < n; j += 1024) {
      unsigned key = mono_u(score[b * N0 + j]);
      if ((key & pmask) == pref) atomicAdd(&hist[(key >> shift) & 255], 1);
    }
    __syncthreads();
    if (t == 0) {
      int r = s_r, acc = 0, d = 255;
      for (; d >= 0; --d) {
        if (acc + hist[d] >= r) break;
        acc += hist[d];
      }
      s_gt += acc;
      s_r = r - acc;
      s_pref = pref | ((unsigned)d << shift);
    }
    __syncthreads();
  }
  if (t == 0) {
    vstar[b] = s_pref;
    quota[b] = k - s_gt;   // ties (by lowest index) that get selected
  }
}

// ---------- mapping old->new (or -1), jax.lax.top_k tie semantics ----------
__global__ __launch_bounds__(1024) void k_map(const float* __restrict__ score,
                                              const unsigned* __restrict__ vstar,
                                              const int* __restrict__ quota,
                                              int* __restrict__ mp, int n) {
  __shared__ int wt[16], ws2[16];
  __shared__ int bases[2];
  int b = blockIdx.x;
  int t = threadIdx.x, lane = t & 63, wid = t >> 6;
  if (t == 0) { bases[0] = 0; bases[1] = 0; }
  __syncthreads();
  unsigned vs = vstar[b];
  int q = quota[b];
  for (int base = 0; base < n; base += 1024) {
    int j = base + t;
    unsigned key = (j < n) ? mono_u(score[b * N0 + j]) : 0u;
    int gt = (j < n) && (key > vs);
    int tie = (j < n) && (key == vs);
    int tinc = wscan_incl(tie, lane);
    if (lane == 63) wt[wid] = tinc;
    __syncthreads();
    int woff = 0;
    for (int w = 0; w < wid; w++) woff += wt[w];
    int tie_excl = bases[0] + woff + tinc - tie;
    int sel = gt | (tie & ((tie_excl < q) ? 1 : 0));
    int sinc = wscan_incl(sel, lane);
    if (lane == 63) ws2[wid] = sinc;
    __syncthreads();
    int woff2 = 0;
    for (int w = 0; w < wid; w++) woff2 += ws2[w];
    if (j < n) mp[b * N0 + j] = sel ? (bases[1] + woff2 + sinc - sel) : -1;
    __syncthreads();
    if (t == 0) {
      int tt = 0, ss = 0;
      for (int w = 0; w < 16; w++) { tt += wt[w]; ss += ws2[w]; }
      bases[0] += tt; bases[1] += ss;
    }
    __syncthreads();
  }
}

// ---------- compact selected rows, scaled by score ----------
__global__ void k_compact(const float* __restrict__ Xin, float* __restrict__ Xout,
                          const int* __restrict__ mp, const float* __restrict__ score, int n) {
  int lane = threadIdx.x & 63, wid = threadIdx.x >> 6;
  int node = blockIdx.x * 4 + wid;
  int b = blockIdx.y;
  if (node >= n) return;
  int m = mp[b * N0 + node];
  if (m < 0) return;
  float val = score[b * N0 + node];
  float2 v = *reinterpret_cast<const float2*>(&Xin[((size_t)b * N0 + node) * NC + lane * 2]);
  v.x *= val; v.y *= val;
  *reinterpret_cast<float2*>(&Xout[((size_t)b * N0 + m) * NC + lane * 2]) = v;
}

// ---------- remap edges in place; dst=-1 marks invalid ----------
__global__ void k_remap(int* __restrict__ srcw, int* __restrict__ dstw, const int* __restrict__ mp) {
  int tot = NB * NE;
  for (int i = blockIdx.x * blockDim.x + threadIdx.x; i < tot; i += gridDim.x * blockDim.x) {
    int d = dstw[i];
    if (d < 0) continue;
    int b = i / NE;
    int s = srcw[i];
    int ns = mp[b * N0 + s], nd = mp[b * N0 + d];
    if (ns >= 0 && nd >= 0) { srcw[i] = ns; dstw[i] = nd; }
    else { srcw[i] = 0; dstw[i] = -1; }
  }
}

// ---------- readout buffers ----------
__global__ void k_zbuf(int* __restrict__ maxbuf, float* __restrict__ sumbuf) {
  int i = blockIdx.x * blockDim.x + threadIdx.x;
  if (i < NB * NC) { maxbuf[i] = (int)0x80000000; sumbuf[i] = 0.f; }
}

__global__ void k_readout(const float* __restrict__ X, int* __restrict__ maxbuf,
                          float* __restrict__ sumbuf, int n) {
  __shared__ float smx[128], ssm[128];
  int b = blockIdx.y;
  int nchunk = gridDim.x;
  int rows = (n + nchunk - 1) / nchunk;
  int lo = blockIdx.x * rows;
  int hi = min(lo + rows, n);
  int c = threadIdx.x & 127, h = threadIdx.x >> 7;
  float mx = -INFINITY, sm = 0.f;
  for (int r = lo + h; r < hi; r += 2) {
    float v = X[((size_t)b * N0 + r) * NC + c];
    mx = fmaxf(mx, v);
    sm += v;
  }
  if (h) { smx[c] = mx; ssm[c] = sm; }
  __syncthreads();
  if (!h) {
    mx = fmaxf(mx, smx[c]);
    sm += ssm[c];
    atomicMax(&maxbuf[b * NC + c], f2ikey(mx));
    atomicAdd(&sumbuf[b * NC + c], sm);
  }
}

__global__ void k_addro(const int* __restrict__ maxbuf, const float* __restrict__ sumbuf,
                        float* __restrict__ r, int nout) {
  int i = blockIdx.x * blockDim.x + threadIdx.x;
  if (i >= NB * NC) return;
  int b = i >> 7, c = i & 127;
  r[b * 256 + c] += ikey2f(maxbuf[i]);
  r[b * 256 + 128 + c] += sumbuf[i] / (float)nout;
}

// ---------- tiny predictor MLP ----------
__global__ __launch_bounds__(256) void k_pred(const float* __restrict__ r,
                                              const float* __restrict__ q1w, const float* __restrict__ q1b,
                                              const float* __restrict__ q2w, const float* __restrict__ q2b,
                                              const float* __restrict__ q3w, const float* __restrict__ q3b,
                                              float* __restrict__ out) {
  __shared__ float rr[256], h1[128], h2[64];
  int b = blockIdx.x, t = threadIdx.x;
  rr[t] = r[b * 256 + t];
  __syncthreads();
  if (t < 128) {
    float s = q1b[t];
    for (int j = 0; j < 256; j++) s = fmaf(rr[j], q1w[j * 128 + t], s);
    h1[t] = fmaxf(s, 0.f);
  }
  __syncthreads();
  if (t < 64) {
    float s = q2b[t];
    for (int j = 0; j < 128; j++) s = fmaf(h1[j], q2w[j * 64 + t], s);
    h2[t] = fmaxf(s, 0.f);
  }
  __syncthreads();
  if (t < 2) {
    float s = q3b[t];
    for (int j = 0; j < 64; j++) s = fmaf(h2[j], q3w[j * 2 + t], s);
    out[b * 2 + t] = s;
  }
}

// ---------- host orchestration ----------
extern "C" void kernel_launch(void* const* d_in, const int* in_sizes, int n_in,
                              void* d_out, int out_size, void* d_ws, size_t ws_size,
                              hipStream_t stream) {
  const float* x = (const float*)d_in[0];
  const int* src = (const int*)d_in[1];
  const int* dst = (const int*)d_in[2];
  const float* q1w = (const float*)d_in[23];
  const float* q1b = (const float*)d_in[24];
  const float* q2w = (const float*)d_in[25];
  const float* q2b = (const float*)d_in[26];
  const float* q3w = (const float*)d_in[27];
  const float* q3b = (const float*)d_in[28];

  char* p = (char*)d_ws;
  auto alloc = [&](size_t bytes) {
    char* q = p;
    p += (bytes + 255) & ~(size_t)255;
    return q;
  };
  float* Xa = (float*)alloc((size_t)NB * N0 * NC * 4);
  float* Xb = (float*)alloc((size_t)NB * N0 * NC * 4);
  int* srcw = (int*)alloc((size_t)NB * NE * 4);
  int* dstw = (int*)alloc((size_t)NB * NE * 4);
  int* elist = (int*)alloc((size_t)NB * NE * 4);
  int* cnt = (int*)alloc((size_t)NB * N0 * 4);
  int* offs = (int*)alloc((size_t)NB * N0 * 4);
  int* cursor = (int*)alloc((size_t)NB * N0 * 4);
  float* score = (float*)alloc((size_t)NB * N0 * 4);
  int* mp = (int*)alloc((size_t)NB * N0 * 4);
  unsigned* vstar = (unsigned*)alloc(256);
  int* quota = (int*)alloc(256);
  int* maxbuf = (int*)alloc(NB * NC * 4);
  float* sumbuf = (float*)alloc(NB * NC * 4);
  float* r = (float*)alloc(NB * 256 * 4);

  hipMemcpyAsync(Xa, x, (size_t)NB * N0 * NC * 4, hipMemcpyDeviceToDevice, stream);
  k_init<<<1024, 256, 0, stream>>>(src, dst, srcw, dstw, r);

  static const int NSv[4] = {16384, 13108, 10487, 8390};
  static const int KSv[4] = {13108, 10487, 8390, 6712};
  float* cur = Xa;
  float* tmp = Xb;
  for (int i = 0; i < 4; i++) {
    int n = NSv[i], k = KSv[i];
    const float* w1 = (const float*)d_in[3 + i * 5 + 0];
    const float* b1 = (const float*)d_in[3 + i * 5 + 1];
    const float* w2 = (const float*)d_in[3 + i * 5 + 2];
    const float* b2 = (const float*)d_in[3 + i * 5 + 3];
    const float* pw = (const float*)d_in[3 + i * 5 + 4];

    // --- CSR build (deterministic gather replaces scatter atomics) ---
    hipMemsetAsync(cnt, 0, (size_t)NB * N0 * 4, stream);
    k_count<<<1024, 256, 0, stream>>>(dstw, cnt);
    k_scan<<<NB, 1024, 0, stream>>>(cnt, offs, cursor);
    k_fill<<<1024, 256, 0, stream>>>(srcw, dstw, cursor, elist);

    dim3 gs((n + 3) / 4, NB);
    k_gather<<<gs, 256, 0, stream>>>(cur, tmp, offs, cnt, elist, n);  // h0 = x + agg

    dim3 gg((n + 127) / 128, NB);
    k_gemm<<<gg, 256, 0, stream>>>(tmp, cur, w1, b1, n);   // h = relu(h0 @ w1 + b1)
    k_gemm<<<gg, 256, 0, stream>>>(cur, tmp, w2, b2, n);   // x = relu(h @ w2 + b2)

    k_score<<<gs, 256, 0, stream>>>(tmp, pw, score, n);
    k_select<<<NB, 1024, 0, stream>>>(score, vstar, quota, n, k);
    k_map<<<NB, 1024, 0, stream>>>(score, vstar, quota, mp, n);
    k_compact<<<gs, 256, 0, stream>>>(tmp, cur, mp, score, n);   // cur = pooled x [k rows]
    k_remap<<<1024, 256, 0, stream>>>(srcw, dstw, mp);

    k_zbuf<<<(NB * NC + 255) / 256, 256, 0, stream>>>(maxbuf, sumbuf);
    dim3 gr(32, NB);
    k_readout<<<gr, 256, 0, stream>>>(cur, maxbuf, sumbuf, k);
    k_addro<<<(NB * NC + 255) / 256, 256, 0, stream>>>(maxbuf, sumbuf, r, k);
  }

  k_pred<<<NB, 256, 0, stream>>>(r, q1w, q1b, q2w, q2b, q3w, q3b, (float*)d_out);
}

// Round 3
// 1450.069 us; speedup vs baseline: 2.6274x; 1.1763x over previous
//
#include <hip/hip_runtime.h>
#include <math.h>

#define NB 8
#define N0 16384
#define NC 128
#define NE 98304

// ---------- helpers ----------
__device__ __forceinline__ unsigned mono_u(float f) {
  unsigned u = __float_as_uint(f);
  return (u & 0x80000000u) ? ~u : (u | 0x80000000u);
}
__device__ __forceinline__ int f2ikey(float f) {
  int i = __float_as_int(f);
  return (i >= 0) ? i : (i ^ 0x7fffffff);
}
__device__ __forceinline__ float ikey2f(int k) {
  return __int_as_float(k >= 0 ? k : (k ^ 0x7fffffff));
}

// ---------- init: copy edges, zero cnt, init per-depth readout buffers ----------
__global__ void k_init(const int* __restrict__ src, const int* __restrict__ dst,
                       int* __restrict__ srcw, int* __restrict__ dstw,
                       int* __restrict__ cnt, int* __restrict__ maxbuf, float* __restrict__ sumbuf) {
  int stride = gridDim.x * blockDim.x;
  int i = blockIdx.x * blockDim.x + threadIdx.x;
  for (int j = i; j < NB * NE; j += stride) {
    srcw[j] = src[j];
    dstw[j] = dst[j];
  }
  for (int j = i; j < NB * N0; j += stride) cnt[j] = 0;
  for (int j = i; j < 4 * NB * NC; j += stride) {
    maxbuf[j] = (int)0x80000000;
    sumbuf[j] = 0.f;
  }
}

// ---------- CSR build: count incoming edges per node ----------
__global__ void k_count(const int* __restrict__ dstw, int* __restrict__ cnt) {
  int tot = NB * NE;
  for (int i = blockIdx.x * blockDim.x + threadIdx.x; i < tot; i += gridDim.x * blockDim.x) {
    int d = dstw[i];
    if (d >= 0) atomicAdd(&cnt[(i / NE) * N0 + d], 1);
  }
}

// ---------- CSR build: per-graph exclusive scan over 16384 counts ----------
__global__ __launch_bounds__(1024) void k_scan(const int* __restrict__ cnt,
                                               int* __restrict__ offs, int* __restrict__ cursor) {
  __shared__ int ws[1024];
  int b = blockIdx.x, t = threadIdx.x;
  int base = b * N0 + t * 16;
  int loc[16];
  int s = 0;
#pragma unroll
  for (int j = 0; j < 16; j++) { loc[j] = cnt[base + j]; s += loc[j]; }
  ws[t] = s;
  __syncthreads();
  for (int o = 1; o < 1024; o <<= 1) {
    int v = (t >= o) ? ws[t - o] : 0;
    __syncthreads();
    ws[t] += v;
    __syncthreads();
  }
  int excl = ws[t] - s;
#pragma unroll
  for (int j = 0; j < 16; j++) {
    offs[base + j] = excl;
    cursor[base + j] = excl;
    excl += loc[j];
  }
}

// ---------- CSR build: fill edge list ----------
__global__ void k_fill(const int* __restrict__ srcw, const int* __restrict__ dstw,
                       int* __restrict__ cursor, int* __restrict__ elist) {
  int tot = NB * NE;
  for (int i = blockIdx.x * blockDim.x + threadIdx.x; i < tot; i += gridDim.x * blockDim.x) {
    int d = dstw[i];
    if (d < 0) continue;
    int b = i / NE;
    int pos = atomicAdd(&cursor[b * N0 + d], 1);
    elist[b * NE + pos] = srcw[i];
  }
}

// ---------- gather: H[node] = X[node] + sum_{src in CSR[node]} X[src] ----------
__global__ void k_gather(const float* __restrict__ X, float* __restrict__ H,
                         const int* __restrict__ offs, const int* __restrict__ cnt,
                         const int* __restrict__ elist, int n) {
  int lane = threadIdx.x & 63, wid = threadIdx.x >> 6;
  int node = blockIdx.x * 4 + wid;
  int b = blockIdx.y;
  if (node >= n) return;
  int off = offs[b * N0 + node];
  int deg = cnt[b * N0 + node];
  const float* Xb = X + (size_t)b * N0 * NC;
  float2 acc = *reinterpret_cast<const float2*>(&Xb[(size_t)node * NC + lane * 2]);
  for (int base = 0; base < deg; base += 64) {
    int m = min(64, deg - base);
    int eid = (lane < m) ? elist[b * NE + off + base + lane] : 0;
    for (int j = 0; j < m; j++) {
      int s = __shfl(eid, j);
      float2 v = *reinterpret_cast<const float2*>(&Xb[(size_t)s * NC + lane * 2]);
      acc.x += v.x;
      acc.y += v.y;
    }
  }
  *reinterpret_cast<float2*>(&H[((size_t)b * N0 + node) * NC + lane * 2]) = acc;
}

// ---------- GEMM: out = relu(Xin @ W + bias); optional fused score ----------
// 512 threads, tile 128 rows x 128 cols, thread = 4 rows x 8 cols.
// X staged transposed in LDS (one broadcast b128 per k); W streamed from L1/L2.
template <bool SCORE>
__global__ __launch_bounds__(512, 4) void k_gemm(const float* __restrict__ Xin,
                                                 float* __restrict__ Xout,
                                                 const float* __restrict__ W,
                                                 const float* __restrict__ bias,
                                                 const float* __restrict__ pw,
                                                 float* __restrict__ score, int n) {
  __shared__ float Xs[128 * 132];  // [k][row], 67.6 KB
  __shared__ float s_nrm;
  int b = blockIdx.y;
  int r0 = blockIdx.x * 128;
  int t = threadIdx.x;
  const float* Xg = Xin + (size_t)b * N0 * NC;

  if (SCORE && t < 64) {
    float2 pp = reinterpret_cast<const float2*>(pw)[t];
    float s = pp.x * pp.x + pp.y * pp.y;
#pragma unroll
    for (int o = 32; o > 0; o >>= 1) s += __shfl_xor(s, o);
    if (t == 0) s_nrm = sqrtf(s);
  }

  // stage X transposed: chunk = (col c, row-quad r4)
#pragma unroll
  for (int l = 0; l < 8; l++) {
    int id = t + l * 512;
    int c = id & 127;
    int r4 = id >> 7;  // 0..31
    float v[4];
#pragma unroll
    for (int i = 0; i < 4; i++) {
      int row = r0 + r4 * 4 + i;
      v[i] = (row < n) ? Xg[(size_t)row * NC + c] : 0.f;
    }
    *reinterpret_cast<float4*>(&Xs[c * 132 + r4 * 4]) = make_float4(v[0], v[1], v[2], v[3]);
  }
  __syncthreads();

  int tx = t & 15, ty = t >> 4;  // ty 0..31
  const float* wp0 = W + tx * 4;
  const float* wp1 = W + 64 + tx * 4;
  const float* xsp = &Xs[ty * 4];

  float acc[4][8];
#pragma unroll
  for (int i = 0; i < 4; i++)
#pragma unroll
    for (int j = 0; j < 8; j++) acc[i][j] = 0.f;

#pragma unroll 4
  for (int k = 0; k < 128; k++) {
    float4 a4 = *reinterpret_cast<const float4*>(xsp + k * 132);
    float4 w0 = *reinterpret_cast<const float4*>(wp0 + k * 128);
    float4 w1 = *reinterpret_cast<const float4*>(wp1 + k * 128);
    float av[4] = {a4.x, a4.y, a4.z, a4.w};
    float wv[8] = {w0.x, w0.y, w0.z, w0.w, w1.x, w1.y, w1.z, w1.w};
#pragma unroll
    for (int i = 0; i < 4; i++)
#pragma unroll
      for (int j = 0; j < 8; j++) acc[i][j] = fmaf(av[i], wv[j], acc[i][j]);
  }

  float4 bv0 = *reinterpret_cast<const float4*>(bias + tx * 4);
  float4 bv1 = *reinterpret_cast<const float4*>(bias + 64 + tx * 4);
  float bb[8] = {bv0.x, bv0.y, bv0.z, bv0.w, bv1.x, bv1.y, bv1.z, bv1.w};
  float pp[8];
  if (SCORE) {
    float4 p0 = *reinterpret_cast<const float4*>(pw + tx * 4);
    float4 p1 = *reinterpret_cast<const float4*>(pw + 64 + tx * 4);
    pp[0] = p0.x; pp[1] = p0.y; pp[2] = p0.z; pp[3] = p0.w;
    pp[4] = p1.x; pp[5] = p1.y; pp[6] = p1.z; pp[7] = p1.w;
  }

#pragma unroll
  for (int i = 0; i < 4; i++) {
    int row = r0 + ty * 4 + i;
    float o[8];
#pragma unroll
    for (int j = 0; j < 8; j++) o[j] = fmaxf(acc[i][j] + bb[j], 0.f);
    if (row < n) {
      float4* op = reinterpret_cast<float4*>(&Xout[((size_t)b * N0 + row) * NC + tx * 4]);
      op[0] = make_float4(o[0], o[1], o[2], o[3]);
      op[16] = make_float4(o[4], o[5], o[6], o[7]);  // +64 floats
    }
    if (SCORE) {
      float dot = 0.f;
#pragma unroll
      for (int j = 0; j < 8; j++) dot = fmaf(o[j], pp[j], dot);
#pragma unroll
      for (int ofs = 1; ofs < 16; ofs <<= 1) dot += __shfl_xor(dot, ofs);
      if (tx == 0 && row < n) score[b * N0 + row] = tanhf(dot / s_nrm);
    }
  }
}

// ---------- top-k threshold via 4-pass radix select ----------
__global__ __launch_bounds__(1024) void k_select(const float* __restrict__ score,
                                                 unsigned* __restrict__ vstar, int* __restrict__ quota,
                                                 int n, int k) {
  __shared__ int hist[256];
  __shared__ unsigned s_pref;
  __shared__ int s_r, s_gt;
  int b = blockIdx.x, t = threadIdx.x, lane = t & 63;
  if (t == 0) { s_pref = 0u; s_r = k; s_gt = 0; }
  __syncthreads();
  for (int pass = 0; pass < 4; ++pass) {
    int shift = 24 - pass * 8;
    if (t < 256) hist[t] = 0;
    __syncthreads();
    unsigned pref = s_pref;
    unsigned pmask = (pass == 0) ? 0u : (0xFFFFFFFFu << (shift + 8));
    for (int j0 = 0; j0 < n; j0 += 1024) {
      int j = j0 + t;
      unsigned key = (j < n) ? mono_u(score[b * N0 + j]) : 0u;
      unsigned d = (key >> shift) & 255;
      int contrib = (j < n) && ((key & pmask) == pref);
      unsigned long long bal = __ballot(contrib);
      if (bal == 0) continue;
      int fl = __ffsll((long long)bal) - 1;
      unsigned dref = __shfl(d, fl);
      if (__all(!contrib || d == dref)) {
        if (lane == fl) atomicAdd(&hist[dref], (int)__popcll(bal));
      } else if (contrib) {
        atomicAdd(&hist[d], 1);
      }
    }
    __syncthreads();
    if (t == 0) {
      int r = s_r, acc = 0, d = 255;
      for (; d >= 0; --d) {
        if (acc + hist[d] >= r) break;
        acc += hist[d];
      }
      s_gt += acc;
      s_r = r - acc;
      s_pref = pref | ((unsigned)d << shift);
    }
    __syncthreads();
  }
  if (t == 0) {
    vstar[b] = s_pref;
    quota[b] = k - s_gt;
  }
}

// ---------- map phase 1: per-1024-chunk gt/tie counts ----------
__global__ __launch_bounds__(1024) void k_map_cnt(const float* __restrict__ score,
                                                  const unsigned* __restrict__ vstar,
                                                  int* __restrict__ gcnt, int* __restrict__ tcnt, int n) {
  __shared__ int wg[16], wt[16];
  int b = blockIdx.y, chunk = blockIdx.x, t = threadIdx.x;
  int lane = t & 63, wid = t >> 6;
  int j = chunk * 1024 + t;
  unsigned vs = vstar[b];
  unsigned key = (j < n) ? mono_u(score[b * N0 + j]) : 0u;
  int gt = (j < n) && (key > vs);
  int tie = (j < n) && (key == vs);
  unsigned long long bg = __ballot(gt), bt = __ballot(tie);
  if (lane == 0) { wg[wid] = (int)__popcll(bg); wt[wid] = (int)__popcll(bt); }
  __syncthreads();
  if (t == 0) {
    int g = 0, tt = 0;
    for (int w = 0; w < 16; w++) { g += wg[w]; tt += wt[w]; }
    gcnt[b * 16 + chunk] = g;
    tcnt[b * 16 + chunk] = tt;
  }
}

// ---------- map phase 2: assign new ids with jax.lax.top_k tie semantics ----------
__global__ __launch_bounds__(1024) void k_map_wr(const float* __restrict__ score,
                                                 const unsigned* __restrict__ vstar,
                                                 const int* __restrict__ quota,
                                                 const int* __restrict__ gcnt, const int* __restrict__ tcnt,
                                                 int* __restrict__ mp, int n) {
  __shared__ int wg[16], wt[16];
  __shared__ int s_gb, s_tb;
  int b = blockIdx.y, chunk = blockIdx.x, t = threadIdx.x;
  int lane = t & 63, wid = t >> 6;
  if (t == 0) {
    int gb = 0, tb = 0;
    for (int c = 0; c < chunk; c++) { gb += gcnt[b * 16 + c]; tb += tcnt[b * 16 + c]; }
    s_gb = gb; s_tb = tb;
  }
  int j = chunk * 1024 + t;
  unsigned vs = vstar[b];
  int q = quota[b];
  unsigned key = (j < n) ? mono_u(score[b * N0 + j]) : 0u;
  int gt = (j < n) && (key > vs);
  int tie = (j < n) && (key == vs);
  unsigned long long bg = __ballot(gt), bt = __ballot(tie);
  if (lane == 0) { wg[wid] = (int)__popcll(bg); wt[wid] = (int)__popcll(bt); }
  __syncthreads();
  if (j >= n) return;
  unsigned long long ltm = (lane == 63) ? ~0ull >> 1 : ((1ull << lane) - 1);
  int gloc = (int)__popcll(bg & ltm);
  int tloc = (int)__popcll(bt & ltm);
  for (int w = 0; w < 16; w++) {
    if (w < wid) { gloc += wg[w]; tloc += wt[w]; }
  }
  int tie_rank = s_tb + tloc;  // global ties strictly before j
  int sel = gt || (tie && tie_rank < q);
  int pos = s_gb + gloc + min(tie_rank, q);
  mp[b * N0 + j] = sel ? pos : -1;
}

// ---------- compact selected rows, scaled by score ----------
__global__ void k_compact(const float* __restrict__ Xin, float* __restrict__ Xout,
                          const int* __restrict__ mp, const float* __restrict__ score, int n) {
  int lane = threadIdx.x & 63, wid = threadIdx.x >> 6;
  int node = blockIdx.x * 4 + wid;
  int b = blockIdx.y;
  if (node >= n) return;
  int m = mp[b * N0 + node];
  if (m < 0) return;
  float val = score[b * N0 + node];
  float2 v = *reinterpret_cast<const float2*>(&Xin[((size_t)b * N0 + node) * NC + lane * 2]);
  v.x *= val; v.y *= val;
  *reinterpret_cast<float2*>(&Xout[((size_t)b * N0 + m) * NC + lane * 2]) = v;
}

// ---------- remap edges in place; also zero cnt for next depth ----------
__global__ void k_remap(int* __restrict__ srcw, int* __restrict__ dstw,
                        const int* __restrict__ mp, int* __restrict__ cnt) {
  int tot = NB * NE;
  int tid = blockIdx.x * blockDim.x + threadIdx.x;
  int stride = gridDim.x * blockDim.x;
  for (int i = tid; i < tot; i += stride) {
    int d = dstw[i];
    if (d < 0) continue;
    int b = i / NE;
    int s = srcw[i];
    int ns = mp[b * N0 + s], nd = mp[b * N0 + d];
    if (ns >= 0 && nd >= 0) { srcw[i] = ns; dstw[i] = nd; }
    else { srcw[i] = 0; dstw[i] = -1; }
  }
  for (int j = tid; j < NB * N0; j += stride) cnt[j] = 0;
}

// ---------- readout: per-channel max + sum into per-depth buffers ----------
__global__ void k_readout(const float* __restrict__ X, int* __restrict__ maxbuf,
                          float* __restrict__ sumbuf, int n) {
  __shared__ float smx[128], ssm[128];
  int b = blockIdx.y;
  int nchunk = gridDim.x;
  int rows = (n + nchunk - 1) / nchunk;
  int lo = blockIdx.x * rows;
  int hi = min(lo + rows, n);
  int c = threadIdx.x & 127, h = threadIdx.x >> 7;
  float mx = -INFINITY, sm = 0.f;
  for (int r = lo + h; r < hi; r += 2) {
    float v = X[((size_t)b * N0 + r) * NC + c];
    mx = fmaxf(mx, v);
    sm += v;
  }
  if (h) { smx[c] = mx; ssm[c] = sm; }
  __syncthreads();
  if (!h) {
    mx = fmaxf(mx, smx[c]);
    sm += ssm[c];
    atomicMax(&maxbuf[b * NC + c], f2ikey(mx));
    atomicAdd(&sumbuf[b * NC + c], sm);
  }
}

// ---------- predictor MLP (folds readout-sum across depths) ----------
__global__ __launch_bounds__(256) void k_pred(const int* __restrict__ maxbuf,
                                              const float* __restrict__ sumbuf,
                                              const float* __restrict__ q1w, const float* __restrict__ q1b,
                                              const float* __restrict__ q2w, const float* __restrict__ q2b,
                                              const float* __restrict__ q3w, const float* __restrict__ q3b,
                                              float* __restrict__ out) {
  __shared__ float rr[256], h1[128], h2[64];
  int b = blockIdx.x, t = threadIdx.x;
  const float kdiv[4] = {13108.f, 10487.f, 8390.f, 6712.f};
  float acc = 0.f;
#pragma unroll
  for (int d = 0; d < 4; d++) {
    if (t < 128) acc += ikey2f(maxbuf[d * NB * NC + b * NC + t]);
    else acc += sumbuf[d * NB * NC + b * NC + (t - 128)] / kdiv[d];
  }
  rr[t] = acc;
  __syncthreads();
  if (t < 128) {
    float s = q1b[t];
    for (int j = 0; j < 256; j++) s = fmaf(rr[j], q1w[j * 128 + t], s);
    h1[t] = fmaxf(s, 0.f);
  }
  __syncthreads();
  if (t < 64) {
    float s = q2b[t];
    for (int j = 0; j < 128; j++) s = fmaf(h1[j], q2w[j * 64 + t], s);
    h2[t] = fmaxf(s, 0.f);
  }
  __syncthreads();
  if (t < 2) {
    float s = q3b[t];
    for (int j = 0; j < 64; j++) s = fmaf(h2[j], q3w[j * 2 + t], s);
    out[b * 2 + t] = s;
  }
}

// ---------- host orchestration ----------
extern "C" void kernel_launch(void* const* d_in, const int* in_sizes, int n_in,
                              void* d_out, int out_size, void* d_ws, size_t ws_size,
                              hipStream_t stream) {
  const float* x = (const float*)d_in[0];
  const int* src = (const int*)d_in[1];
  const int* dst = (const int*)d_in[2];
  const float* q1w = (const float*)d_in[23];
  const float* q1b = (const float*)d_in[24];
  const float* q2w = (const float*)d_in[25];
  const float* q2b = (const float*)d_in[26];
  const float* q3w = (const float*)d_in[27];
  const float* q3b = (const float*)d_in[28];

  char* p = (char*)d_ws;
  auto alloc = [&](size_t bytes) {
    char* q = p;
    p += (bytes + 255) & ~(size_t)255;
    return q;
  };
  float* Xa = (float*)alloc((size_t)NB * N0 * NC * 4);
  float* Xb = (float*)alloc((size_t)NB * N0 * NC * 4);
  int* srcw = (int*)alloc((size_t)NB * NE * 4);
  int* dstw = (int*)alloc((size_t)NB * NE * 4);
  int* elist = (int*)alloc((size_t)NB * NE * 4);
  int* cnt = (int*)alloc((size_t)NB * N0 * 4);
  int* offs = (int*)alloc((size_t)NB * N0 * 4);
  int* cursor = (int*)alloc((size_t)NB * N0 * 4);
  float* score = (float*)alloc((size_t)NB * N0 * 4);
  int* mp = (int*)alloc((size_t)NB * N0 * 4);
  unsigned* vstar = (unsigned*)alloc(256);
  int* quota = (int*)alloc(256);
  int* gcnt = (int*)alloc(NB * 16 * 4);
  int* tcnt = (int*)alloc(NB * 16 * 4);
  int* maxbuf = (int*)alloc(4 * NB * NC * 4);
  float* sumbuf = (float*)alloc(4 * NB * NC * 4);

  hipMemcpyAsync(Xa, x, (size_t)NB * N0 * NC * 4, hipMemcpyDeviceToDevice, stream);
  k_init<<<2048, 256, 0, stream>>>(src, dst, srcw, dstw, cnt, maxbuf, sumbuf);

  static const int NSv[4] = {16384, 13108, 10487, 8390};
  static const int KSv[4] = {13108, 10487, 8390, 6712};
  float* cur = Xa;
  float* tmp = Xb;
  for (int i = 0; i < 4; i++) {
    int n = NSv[i], k = KSv[i];
    const float* w1 = (const float*)d_in[3 + i * 5 + 0];
    const float* b1 = (const float*)d_in[3 + i * 5 + 1];
    const float* w2 = (const float*)d_in[3 + i * 5 + 2];
    const float* b2 = (const float*)d_in[3 + i * 5 + 3];
    const float* pw = (const float*)d_in[3 + i * 5 + 4];

    k_count<<<1024, 256, 0, stream>>>(dstw, cnt);
    k_scan<<<NB, 1024, 0, stream>>>(cnt, offs, cursor);
    k_fill<<<1024, 256, 0, stream>>>(srcw, dstw, cursor, elist);

    dim3 gs((n + 3) / 4, NB);
    k_gather<<<gs, 256, 0, stream>>>(cur, tmp, offs, cnt, elist, n);  // h0 = x + agg

    dim3 gg((n + 127) / 128, NB);
    k_gemm<false><<<gg, 512, 0, stream>>>(tmp, cur, w1, b1, nullptr, nullptr, n);
    k_gemm<true><<<gg, 512, 0, stream>>>(cur, tmp, w2, b2, pw, score, n);

    k_select<<<NB, 1024, 0, stream>>>(score, vstar, quota, n, k);
    dim3 gm(16, NB);
    k_map_cnt<<<gm, 1024, 0, stream>>>(score, vstar, gcnt, tcnt, n);
    k_map_wr<<<gm, 1024, 0, stream>>>(score, vstar, quota, gcnt, tcnt, mp, n);

    k_compact<<<gs, 256, 0, stream>>>(tmp, cur, mp, score, n);   // cur = pooled x
    k_remap<<<1024, 256, 0, stream>>>(srcw, dstw, mp, cnt);

    dim3 gr(32, NB);
    k_readout<<<gr, 256, 0, stream>>>(cur, maxbuf + i * NB * NC, sumbuf + i * NB * NC, k);
  }

  k_pred<<<NB, 256, 0, stream>>>(maxbuf, sumbuf, q1w, q1b, q2w, q2b, q3w, q3b, (float*)d_out);
}

// Round 4
// 1195.584 us; speedup vs baseline: 3.1867x; 1.2129x over previous
//
#include <hip/hip_runtime.h>
#include <math.h>

#define NB 8
#define N0 16384
#define NC 128
#define NE 98304

typedef unsigned short ushort_t;
using short8 = __attribute__((ext_vector_type(8))) short;
using f32x4 = __attribute__((ext_vector_type(4))) float;

// ---------- helpers ----------
__device__ __forceinline__ unsigned mono_u(float f) {
  unsigned u = __float_as_uint(f);
  return (u & 0x80000000u) ? ~u : (u | 0x80000000u);
}
__device__ __forceinline__ int f2ikey(float f) {
  int i = __float_as_int(f);
  return (i >= 0) ? i : (i ^ 0x7fffffff);
}
__device__ __forceinline__ float ikey2f(int k) {
  return __int_as_float(k >= 0 ? k : (k ^ 0x7fffffff));
}
__device__ __forceinline__ ushort_t f2bf_rne(float f) {
  unsigned u = __float_as_uint(f);
  unsigned r = u + 0x7fffu + ((u >> 16) & 1u);
  return (ushort_t)(r >> 16);
}

// ---------- init: copy edges, zero cnt, init per-depth readout buffers ----------
__global__ void k_init(const int* __restrict__ src, const int* __restrict__ dst,
                       int* __restrict__ srcw, int* __restrict__ dstw,
                       int* __restrict__ cnt, int* __restrict__ maxbuf, float* __restrict__ sumbuf) {
  int stride = gridDim.x * blockDim.x;
  int i = blockIdx.x * blockDim.x + threadIdx.x;
  for (int j = i; j < NB * NE; j += stride) {
    srcw[j] = src[j];
    dstw[j] = dst[j];
  }
  for (int j = i; j < NB * N0; j += stride) cnt[j] = 0;
  for (int j = i; j < 4 * NB * NC; j += stride) {
    maxbuf[j] = (int)0x80000000;
    sumbuf[j] = 0.f;
  }
}

// ---------- weight prep: W[k][c] f32 -> Wt[c][k] bf16 ----------
__global__ void k_wprep(const float* __restrict__ W, ushort_t* __restrict__ Wt) {
  int id = blockIdx.x * blockDim.x + threadIdx.x;
  if (id >= NC * NC) return;
  int k = id >> 7, c = id & 127;
  Wt[c * NC + k] = f2bf_rne(W[id]);
}

// ---------- CSR build: count incoming edges per node ----------
__global__ void k_count(const int* __restrict__ dstw, int* __restrict__ cnt) {
  int tot = NB * NE;
  for (int i = blockIdx.x * blockDim.x + threadIdx.x; i < tot; i += gridDim.x * blockDim.x) {
    int d = dstw[i];
    if (d >= 0) atomicAdd(&cnt[(i / NE) * N0 + d], 1);
  }
}

// ---------- CSR build: per-graph exclusive scan over 16384 counts ----------
__global__ __launch_bounds__(1024) void k_scan(const int* __restrict__ cnt,
                                               int* __restrict__ offs, int* __restrict__ cursor) {
  __shared__ int ws[1024];
  int b = blockIdx.x, t = threadIdx.x;
  int base = b * N0 + t * 16;
  int loc[16];
  int s = 0;
#pragma unroll
  for (int j = 0; j < 16; j++) { loc[j] = cnt[base + j]; s += loc[j]; }
  ws[t] = s;
  __syncthreads();
  for (int o = 1; o < 1024; o <<= 1) {
    int v = (t >= o) ? ws[t - o] : 0;
    __syncthreads();
    ws[t] += v;
    __syncthreads();
  }
  int excl = ws[t] - s;
#pragma unroll
  for (int j = 0; j < 16; j++) {
    offs[base + j] = excl;
    cursor[base + j] = excl;
    excl += loc[j];
  }
}

// ---------- CSR build: fill edge list ----------
__global__ void k_fill(const int* __restrict__ srcw, const int* __restrict__ dstw,
                       int* __restrict__ cursor, int* __restrict__ elist) {
  int tot = NB * NE;
  for (int i = blockIdx.x * blockDim.x + threadIdx.x; i < tot; i += gridDim.x * blockDim.x) {
    int d = dstw[i];
    if (d < 0) continue;
    int b = i / NE;
    int pos = atomicAdd(&cursor[b * N0 + d], 1);
    elist[b * NE + pos] = srcw[i];
  }
}

// ---------- gather: H[node] = X[node] + sum_{src in CSR[node]} X[src] ----------
__global__ void k_gather(const float* __restrict__ X, float* __restrict__ H,
                         const int* __restrict__ offs, const int* __restrict__ cnt,
                         const int* __restrict__ elist, int n) {
  int lane = threadIdx.x & 63, wid = threadIdx.x >> 6;
  int node = blockIdx.x * 4 + wid;
  int b = blockIdx.y;
  if (node >= n) return;
  int off = offs[b * N0 + node];
  int deg = cnt[b * N0 + node];
  const float* Xb = X + (size_t)b * N0 * NC;
  float2 acc = *reinterpret_cast<const float2*>(&Xb[(size_t)node * NC + lane * 2]);
  for (int base = 0; base < deg; base += 64) {
    int m = min(64, deg - base);
    int eid = (lane < m) ? elist[b * NE + off + base + lane] : 0;
    for (int j = 0; j < m; j++) {
      int s = __shfl(eid, j);
      float2 v = *reinterpret_cast<const float2*>(&Xb[(size_t)s * NC + lane * 2]);
      acc.x += v.x;
      acc.y += v.y;
    }
  }
  *reinterpret_cast<float2*>(&H[((size_t)b * N0 + node) * NC + lane * 2]) = acc;
}

// ---------- bf16 MFMA GEMM: out = relu(Xin @ W + bias); optional fused score ----------
// Block 256 thr = 4 waves; tile 128 rows x 128 cols; wave = 32 rows x 128 cols.
// X tile f32->bf16 staged to LDS [row][k] stride 136 (uniform bank slots).
// W read as bf16 Wt[c][k] from global (L1-resident). MFMA 16x16x32_bf16.
template <bool SCORE>
__global__ __launch_bounds__(256) void k_gemm_mfma(const float* __restrict__ Xin,
                                                   float* __restrict__ Xout,
                                                   const ushort_t* __restrict__ Wt,
                                                   const float* __restrict__ bias,
                                                   const float* __restrict__ pw,
                                                   float* __restrict__ score, int n) {
  __shared__ ushort_t Xs[128 * 136];  // 34.8 KB
  int b = blockIdx.y;
  int r0 = blockIdx.x * 128;
  int t = threadIdx.x;
  const float* Xg = Xin + (size_t)b * N0 * NC;

  // stage X tile as bf16 (RNE), 2048 16B-chunks over 8 passes
#pragma unroll
  for (int p = 0; p < 8; p++) {
    int id = t + p * 256;
    int row = id >> 4, seg = id & 15;
    int grow = r0 + row;
    short8 vh = (short8)0;
    if (grow < n) {
      const float4* gp = reinterpret_cast<const float4*>(&Xg[(size_t)grow * NC + seg * 8]);
      float4 v0 = gp[0], v1 = gp[1];
      vh[0] = (short)f2bf_rne(v0.x); vh[1] = (short)f2bf_rne(v0.y);
      vh[2] = (short)f2bf_rne(v0.z); vh[3] = (short)f2bf_rne(v0.w);
      vh[4] = (short)f2bf_rne(v1.x); vh[5] = (short)f2bf_rne(v1.y);
      vh[6] = (short)f2bf_rne(v1.z); vh[7] = (short)f2bf_rne(v1.w);
    }
    *reinterpret_cast<short8*>(&Xs[row * 136 + seg * 8]) = vh;
  }
  __syncthreads();

  int lane = t & 63, w = t >> 6;
  int li = lane & 15, lg = lane >> 4;
  int rbase = w * 32;

  f32x4 acc[2][8];
#pragma unroll
  for (int rt = 0; rt < 2; rt++)
#pragma unroll
    for (int ct = 0; ct < 8; ct++) acc[rt][ct] = (f32x4)0.f;

#pragma unroll
  for (int ks = 0; ks < 4; ks++) {
    short8 a0 = *reinterpret_cast<const short8*>(&Xs[(rbase + li) * 136 + ks * 32 + lg * 8]);
    short8 a1 = *reinterpret_cast<const short8*>(&Xs[(rbase + 16 + li) * 136 + ks * 32 + lg * 8]);
#pragma unroll
    for (int ct = 0; ct < 8; ct++) {
      short8 bf = *reinterpret_cast<const short8*>(&Wt[(ct * 16 + li) * NC + ks * 32 + lg * 8]);
      acc[0][ct] = __builtin_amdgcn_mfma_f32_16x16x32_bf16(a0, bf, acc[0][ct], 0, 0, 0);
      acc[1][ct] = __builtin_amdgcn_mfma_f32_16x16x32_bf16(a1, bf, acc[1][ct], 0, 0, 0);
    }
  }

  float bv[8], pwv[8];
#pragma unroll
  for (int ct = 0; ct < 8; ct++) {
    bv[ct] = bias[ct * 16 + li];
    if (SCORE) pwv[ct] = pw[ct * 16 + li];
  }
  float nrm = 1.f;
  if (SCORE) {
    float s = 0.f;
#pragma unroll
    for (int ct = 0; ct < 8; ct++) s = fmaf(pwv[ct], pwv[ct], s);
    s += __shfl_xor(s, 1); s += __shfl_xor(s, 2);
    s += __shfl_xor(s, 4); s += __shfl_xor(s, 8);
    nrm = sqrtf(s);
  }

  float* Ob = Xout + (size_t)b * N0 * NC;
#pragma unroll
  for (int rt = 0; rt < 2; rt++) {
#pragma unroll
    for (int j = 0; j < 4; j++) {
      int row = r0 + rbase + rt * 16 + lg * 4 + j;
      bool ok = row < n;
      float dot = 0.f;
#pragma unroll
      for (int ct = 0; ct < 8; ct++) {
        float o = fmaxf(acc[rt][ct][j] + bv[ct], 0.f);
        if (ok) Ob[(size_t)row * NC + ct * 16 + li] = o;
        if (SCORE) dot = fmaf(o, pwv[ct], dot);
      }
      if (SCORE) {
        dot += __shfl_xor(dot, 1); dot += __shfl_xor(dot, 2);
        dot += __shfl_xor(dot, 4); dot += __shfl_xor(dot, 8);
        if (li == 0 && ok) score[b * N0 + row] = tanhf(dot / nrm);
      }
    }
  }
}

// ---------- top-k threshold via 4-pass radix select ----------
__global__ __launch_bounds__(1024) void k_select(const float* __restrict__ score,
                                                 unsigned* __restrict__ vstar, int* __restrict__ quota,
                                                 int n, int k) {
  __shared__ int hist[256];
  __shared__ unsigned s_pref;
  __shared__ int s_r, s_gt;
  int b = blockIdx.x, t = threadIdx.x, lane = t & 63;
  if (t == 0) { s_pref = 0u; s_r = k; s_gt = 0; }
  __syncthreads();
  for (int pass = 0; pass < 4; ++pass) {
    int shift = 24 - pass * 8;
    if (t < 256) hist[t] = 0;
    __syncthreads();
    unsigned pref = s_pref;
    unsigned pmask = (pass == 0) ? 0u : (0xFFFFFFFFu << (shift + 8));
    for (int j0 = 0; j0 < n; j0 += 1024) {
      int j = j0 + t;
      unsigned key = (j < n) ? mono_u(score[b * N0 + j]) : 0u;
      unsigned d = (key >> shift) & 255;
      int contrib = (j < n) && ((key & pmask) == pref);
      unsigned long long bal = __ballot(contrib);
      if (bal == 0) continue;
      int fl = __ffsll((long long)bal) - 1;
      unsigned dref = __shfl(d, fl);
      if (__all(!contrib || d == dref)) {
        if (lane == fl) atomicAdd(&hist[dref], (int)__popcll(bal));
      } else if (contrib) {
        atomicAdd(&hist[d], 1);
      }
    }
    __syncthreads();
    if (t == 0) {
      int r = s_r, acc = 0, d = 255;
      for (; d >= 0; --d) {
        if (acc + hist[d] >= r) break;
        acc += hist[d];
      }
      s_gt += acc;
      s_r = r - acc;
      s_pref = pref | ((unsigned)d << shift);
    }
    __syncthreads();
  }
  if (t == 0) {
    vstar[b] = s_pref;
    quota[b] = k - s_gt;
  }
}

// ---------- map phase 1: per-1024-chunk gt/tie counts ----------
__global__ __launch_bounds__(1024) void k_map_cnt(const float* __restrict__ score,
                                                  const unsigned* __restrict__ vstar,
                                                  int* __restrict__ gcnt, int* __restrict__ tcnt, int n) {
  __shared__ int wg[16], wt[16];
  int b = blockIdx.y, chunk = blockIdx.x, t = threadIdx.x;
  int lane = t & 63, wid = t >> 6;
  int j = chunk * 1024 + t;
  unsigned vs = vstar[b];
  unsigned key = (j < n) ? mono_u(score[b * N0 + j]) : 0u;
  int gt = (j < n) && (key > vs);
  int tie = (j < n) && (key == vs);
  unsigned long long bg = __ballot(gt), bt = __ballot(tie);
  if (lane == 0) { wg[wid] = (int)__popcll(bg); wt[wid] = (int)__popcll(bt); }
  __syncthreads();
  if (t == 0) {
    int g = 0, tt = 0;
    for (int w = 0; w < 16; w++) { g += wg[w]; tt += wt[w]; }
    gcnt[b * 16 + chunk] = g;
    tcnt[b * 16 + chunk] = tt;
  }
}

// ---------- map phase 2: assign new ids with jax.lax.top_k tie semantics ----------
__global__ __launch_bounds__(1024) void k_map_wr(const float* __restrict__ score,
                                                 const unsigned* __restrict__ vstar,
                                                 const int* __restrict__ quota,
                                                 const int* __restrict__ gcnt, const int* __restrict__ tcnt,
                                                 int* __restrict__ mp, int n) {
  __shared__ int wg[16], wt[16];
  __shared__ int s_gb, s_tb;
  int b = blockIdx.y, chunk = blockIdx.x, t = threadIdx.x;
  int lane = t & 63, wid = t >> 6;
  if (t == 0) {
    int gb = 0, tb = 0;
    for (int c = 0; c < chunk; c++) { gb += gcnt[b * 16 + c]; tb += tcnt[b * 16 + c]; }
    s_gb = gb; s_tb = tb;
  }
  int j = chunk * 1024 + t;
  unsigned vs = vstar[b];
  int q = quota[b];
  unsigned key = (j < n) ? mono_u(score[b * N0 + j]) : 0u;
  int gt = (j < n) && (key > vs);
  int tie = (j < n) && (key == vs);
  unsigned long long bg = __ballot(gt), bt = __ballot(tie);
  if (lane == 0) { wg[wid] = (int)__popcll(bg); wt[wid] = (int)__popcll(bt); }
  __syncthreads();
  if (j >= n) return;
  unsigned long long ltm = (lane == 63) ? ~0ull >> 1 : ((1ull << lane) - 1);
  int gloc = (int)__popcll(bg & ltm);
  int tloc = (int)__popcll(bt & ltm);
  for (int w = 0; w < 16; w++) {
    if (w < wid) { gloc += wg[w]; tloc += wt[w]; }
  }
  int tie_rank = s_tb + tloc;
  int sel = gt || (tie && tie_rank < q);
  int pos = s_gb + gloc + min(tie_rank, q);
  mp[b * N0 + j] = sel ? pos : -1;
}

// ---------- compact selected rows, scaled by score ----------
__global__ void k_compact(const float* __restrict__ Xin, float* __restrict__ Xout,
                          const int* __restrict__ mp, const float* __restrict__ score, int n) {
  int lane = threadIdx.x & 63, wid = threadIdx.x >> 6;
  int node = blockIdx.x * 4 + wid;
  int b = blockIdx.y;
  if (node >= n) return;
  int m = mp[b * N0 + node];
  if (m < 0) return;
  float val = score[b * N0 + node];
  float2 v = *reinterpret_cast<const float2*>(&Xin[((size_t)b * N0 + node) * NC + lane * 2]);
  v.x *= val; v.y *= val;
  *reinterpret_cast<float2*>(&Xout[((size_t)b * N0 + m) * NC + lane * 2]) = v;
}

// ---------- remap edges in place; also zero cnt for next depth ----------
__global__ void k_remap(int* __restrict__ srcw, int* __restrict__ dstw,
                        const int* __restrict__ mp, int* __restrict__ cnt) {
  int tot = NB * NE;
  int tid = blockIdx.x * blockDim.x + threadIdx.x;
  int stride = gridDim.x * blockDim.x;
  for (int i = tid; i < tot; i += stride) {
    int d = dstw[i];
    if (d < 0) continue;
    int b = i / NE;
    int s = srcw[i];
    int ns = mp[b * N0 + s], nd = mp[b * N0 + d];
    if (ns >= 0 && nd >= 0) { srcw[i] = ns; dstw[i] = nd; }
    else { srcw[i] = 0; dstw[i] = -1; }
  }
  for (int j = tid; j < NB * N0; j += stride) cnt[j] = 0;
}

// ---------- readout: per-channel max + sum into per-depth buffers ----------
__global__ void k_readout(const float* __restrict__ X, int* __restrict__ maxbuf,
                          float* __restrict__ sumbuf, int n) {
  __shared__ float smx[128], ssm[128];
  int b = blockIdx.y;
  int nchunk = gridDim.x;
  int rows = (n + nchunk - 1) / nchunk;
  int lo = blockIdx.x * rows;
  int hi = min(lo + rows, n);
  int c = threadIdx.x & 127, h = threadIdx.x >> 7;
  float mx = -INFINITY, sm = 0.f;
  for (int r = lo + h; r < hi; r += 2) {
    float v = X[((size_t)b * N0 + r) * NC + c];
    mx = fmaxf(mx, v);
    sm += v;
  }
  if (h) { smx[c] = mx; ssm[c] = sm; }
  __syncthreads();
  if (!h) {
    mx = fmaxf(mx, smx[c]);
    sm += ssm[c];
    atomicMax(&maxbuf[b * NC + c], f2ikey(mx));
    atomicAdd(&sumbuf[b * NC + c], sm);
  }
}

// ---------- predictor MLP (folds readout-sum across depths) ----------
__global__ __launch_bounds__(256) void k_pred(const int* __restrict__ maxbuf,
                                              const float* __restrict__ sumbuf,
                                              const float* __restrict__ q1w, const float* __restrict__ q1b,
                                              const float* __restrict__ q2w, const float* __restrict__ q2b,
                                              const float* __restrict__ q3w, const float* __restrict__ q3b,
                                              float* __restrict__ out) {
  __shared__ float rr[256], h1[128], h2[64];
  int b = blockIdx.x, t = threadIdx.x;
  const float kdiv[4] = {13108.f, 10487.f, 8390.f, 6712.f};
  float acc = 0.f;
#pragma unroll
  for (int d = 0; d < 4; d++) {
    if (t < 128) acc += ikey2f(maxbuf[d * NB * NC + b * NC + t]);
    else acc += sumbuf[d * NB * NC + b * NC + (t - 128)] / kdiv[d];
  }
  rr[t] = acc;
  __syncthreads();
  if (t < 128) {
    float s = q1b[t];
    for (int j = 0; j < 256; j++) s = fmaf(rr[j], q1w[j * 128 + t], s);
    h1[t] = fmaxf(s, 0.f);
  }
  __syncthreads();
  if (t < 64) {
    float s = q2b[t];
    for (int j = 0; j < 128; j++) s = fmaf(h1[j], q2w[j * 64 + t], s);
    h2[t] = fmaxf(s, 0.f);
  }
  __syncthreads();
  if (t < 2) {
    float s = q3b[t];
    for (int j = 0; j < 64; j++) s = fmaf(h2[j], q3w[j * 2 + t], s);
    out[b * 2 + t] = s;
  }
}

// ---------- host orchestration ----------
extern "C" void kernel_launch(void* const* d_in, const int* in_sizes, int n_in,
                              void* d_out, int out_size, void* d_ws, size_t ws_size,
                              hipStream_t stream) {
  const float* x = (const float*)d_in[0];
  const int* src = (const int*)d_in[1];
  const int* dst = (const int*)d_in[2];
  const float* q1w = (const float*)d_in[23];
  const float* q1b = (const float*)d_in[24];
  const float* q2w = (const float*)d_in[25];
  const float* q2b = (const float*)d_in[26];
  const float* q3w = (const float*)d_in[27];
  const float* q3b = (const float*)d_in[28];

  char* p = (char*)d_ws;
  auto alloc = [&](size_t bytes) {
    char* q = p;
    p += (bytes + 255) & ~(size_t)255;
    return q;
  };
  float* Xa = (float*)alloc((size_t)NB * N0 * NC * 4);
  float* Xb = (float*)alloc((size_t)NB * N0 * NC * 4);
  int* srcw = (int*)alloc((size_t)NB * NE * 4);
  int* dstw = (int*)alloc((size_t)NB * NE * 4);
  int* elist = (int*)alloc((size_t)NB * NE * 4);
  int* cnt = (int*)alloc((size_t)NB * N0 * 4);
  int* offs = (int*)alloc((size_t)NB * N0 * 4);
  int* cursor = (int*)alloc((size_t)NB * N0 * 4);
  float* score = (float*)alloc((size_t)NB * N0 * 4);
  int* mp = (int*)alloc((size_t)NB * N0 * 4);
  unsigned* vstar = (unsigned*)alloc(256);
  int* quota = (int*)alloc(256);
  int* gcnt = (int*)alloc(NB * 16 * 4);
  int* tcnt = (int*)alloc(NB * 16 * 4);
  int* maxbuf = (int*)alloc(4 * NB * NC * 4);
  float* sumbuf = (float*)alloc(4 * NB * NC * 4);
  ushort_t* Wt_all = (ushort_t*)alloc((size_t)8 * NC * NC * 2);

  hipMemcpyAsync(Xa, x, (size_t)NB * N0 * NC * 4, hipMemcpyDeviceToDevice, stream);
  k_init<<<2048, 256, 0, stream>>>(src, dst, srcw, dstw, cnt, maxbuf, sumbuf);
  for (int i = 0; i < 4; i++) {
    k_wprep<<<64, 256, 0, stream>>>((const float*)d_in[3 + i * 5 + 0], Wt_all + (size_t)(2 * i) * NC * NC);
    k_wprep<<<64, 256, 0, stream>>>((const float*)d_in[3 + i * 5 + 2], Wt_all + (size_t)(2 * i + 1) * NC * NC);
  }

  static const int NSv[4] = {16384, 13108, 10487, 8390};
  static const int KSv[4] = {13108, 10487, 8390, 6712};
  float* cur = Xa;
  float* tmp = Xb;
  for (int i = 0; i < 4; i++) {
    int n = NSv[i], k = KSv[i];
    const float* b1 = (const float*)d_in[3 + i * 5 + 1];
    const float* b2 = (const float*)d_in[3 + i * 5 + 3];
    const float* pw = (const float*)d_in[3 + i * 5 + 4];
    const ushort_t* w1t = Wt_all + (size_t)(2 * i) * NC * NC;
    const ushort_t* w2t = Wt_all + (size_t)(2 * i + 1) * NC * NC;

    k_count<<<1024, 256, 0, stream>>>(dstw, cnt);
    k_scan<<<NB, 1024, 0, stream>>>(cnt, offs, cursor);
    k_fill<<<1024, 256, 0, stream>>>(srcw, dstw, cursor, elist);

    dim3 gs((n + 3) / 4, NB);
    k_gather<<<gs, 256, 0, stream>>>(cur, tmp, offs, cnt, elist, n);  // h0 = x + agg

    dim3 gg((n + 127) / 128, NB);
    k_gemm_mfma<false><<<gg, 256, 0, stream>>>(tmp, cur, w1t, b1, nullptr, nullptr, n);
    k_gemm_mfma<true><<<gg, 256, 0, stream>>>(cur, tmp, w2t, b2, pw, score, n);

    k_select<<<NB, 1024, 0, stream>>>(score, vstar, quota, n, k);
    dim3 gm(16, NB);
    k_map_cnt<<<gm, 1024, 0, stream>>>(score, vstar, gcnt, tcnt, n);
    k_map_wr<<<gm, 1024, 0, stream>>>(score, vstar, quota, gcnt, tcnt, mp, n);

    k_compact<<<gs, 256, 0, stream>>>(tmp, cur, mp, score, n);   // cur = pooled x
    k_remap<<<1024, 256, 0, stream>>>(srcw, dstw, mp, cnt);

    dim3 gr(32, NB);
    k_readout<<<gr, 256, 0, stream>>>(cur, maxbuf + i * NB * NC, sumbuf + i * NB * NC, k);
  }

  k_pred<<<NB, 256, 0, stream>>>(maxbuf, sumbuf, q1w, q1b, q2w, q2b, q3w, q3b, (float*)d_out);
}

// Round 5
// 1072.658 us; speedup vs baseline: 3.5519x; 1.1146x over previous
//
#include <hip/hip_runtime.h>
#include <math.h>

#define NB 8
#define N0 16384
#define NC 128
#define NE 98304

typedef unsigned short ushort_t;
using short8 = __attribute__((ext_vector_type(8))) short;
using f32x4 = __attribute__((ext_vector_type(4))) float;

// ---------- helpers ----------
__device__ __forceinline__ unsigned mono_u(float f) {
  unsigned u = __float_as_uint(f);
  return (u & 0x80000000u) ? ~u : (u | 0x80000000u);
}
__device__ __forceinline__ int f2ikey(float f) {
  int i = __float_as_int(f);
  return (i >= 0) ? i : (i ^ 0x7fffffff);
}
__device__ __forceinline__ float ikey2f(int k) {
  return __int_as_float(k >= 0 ? k : (k ^ 0x7fffffff));
}
__device__ __forceinline__ ushort_t f2bf_rne(float f) {
  unsigned u = __float_as_uint(f);
  unsigned r = u + 0x7fffu + ((u >> 16) & 1u);
  return (ushort_t)(r >> 16);
}

// ---------- init: copy edges, depth-0 in-degree count, init readout buffers ----------
// cnt must be pre-zeroed (hipMemsetAsync) before this kernel.
__global__ void k_init(const int* __restrict__ src, const int* __restrict__ dst,
                       int* __restrict__ srcw, int* __restrict__ dstw,
                       int* __restrict__ cnt, int* __restrict__ maxbuf, float* __restrict__ sumbuf) {
  int stride = gridDim.x * blockDim.x;
  int i = blockIdx.x * blockDim.x + threadIdx.x;
  for (int j = i; j < NB * NE; j += stride) {
    int d = dst[j];
    srcw[j] = src[j];
    dstw[j] = d;
    atomicAdd(&cnt[(j / NE) * N0 + d], 1);
  }
  for (int j = i; j < 4 * NB * NC; j += stride) {
    maxbuf[j] = (int)0x80000000;
    sumbuf[j] = 0.f;
  }
}

// ---------- weight prep: W[k][c] f32 -> Wt[c][k] bf16 ----------
__global__ void k_wprep(const float* __restrict__ W, ushort_t* __restrict__ Wt) {
  int id = blockIdx.x * blockDim.x + threadIdx.x;
  if (id >= NC * NC) return;
  int k = id >> 7, c = id & 127;
  Wt[c * NC + k] = f2bf_rne(W[id]);
}

// ---------- CSR build: per-graph exclusive scan; zeroes cnt for reuse ----------
__global__ __launch_bounds__(1024) void k_scan(int* __restrict__ cnt,
                                               int* __restrict__ offs, int* __restrict__ cursor) {
  __shared__ int ws[1024];
  int b = blockIdx.x, t = threadIdx.x;
  int base = b * N0 + t * 16;
  int loc[16];
  int s = 0;
#pragma unroll
  for (int j = 0; j < 16; j++) { loc[j] = cnt[base + j]; s += loc[j]; cnt[base + j] = 0; }
  ws[t] = s;
  __syncthreads();
  for (int o = 1; o < 1024; o <<= 1) {
    int v = (t >= o) ? ws[t - o] : 0;
    __syncthreads();
    ws[t] += v;
    __syncthreads();
  }
  int excl = ws[t] - s;
#pragma unroll
  for (int j = 0; j < 16; j++) {
    offs[base + j] = excl;
    cursor[base + j] = excl;
    excl += loc[j];
  }
}

// ---------- CSR build: fill edge list; cursor ends as end-offset ----------
__global__ void k_fill(const int* __restrict__ srcw, const int* __restrict__ dstw,
                       int* __restrict__ cursor, int* __restrict__ elist) {
  int tot = NB * NE;
  for (int i = blockIdx.x * blockDim.x + threadIdx.x; i < tot; i += gridDim.x * blockDim.x) {
    int d = dstw[i];
    if (d < 0) continue;
    int b = i / NE;
    int pos = atomicAdd(&cursor[b * N0 + d], 1);
    elist[b * NE + pos] = srcw[i];
  }
}

// ---------- gather: H[node] = bf16( X[node] + sum_{src} X[src] ) ----------
// 1D grid, graph = blockIdx.x & 7 -> XCD-pinned (per-XCD L2 holds one graph).
// Half-waves process 2 edges per wave-load (float4/lane, 1 KB/instr).
__global__ void k_gather(const float* __restrict__ X, ushort_t* __restrict__ H,
                         const int* __restrict__ offs, const int* __restrict__ cend,
                         const int* __restrict__ elist, int n) {
  int b = blockIdx.x & 7;
  int chunk = blockIdx.x >> 3;
  int lane = threadIdx.x & 63, wid = threadIdx.x >> 6;
  int node = chunk * 4 + wid;
  if (node >= n) return;
  int off = offs[b * N0 + node];
  int deg = cend[b * N0 + node] - off;
  int h = lane >> 5, c4 = lane & 31;
  const float* Xb = X + (size_t)b * N0 * NC;

  float4 acc0 = make_float4(0.f, 0.f, 0.f, 0.f);
  float4 acc1 = make_float4(0.f, 0.f, 0.f, 0.f);
  if (h == 0) acc0 = *reinterpret_cast<const float4*>(&Xb[(size_t)node * NC + c4 * 4]);

  for (int base = 0; base < deg; base += 64) {
    int m = min(64, deg - base);
    int eid = (lane < m) ? elist[b * NE + off + base + lane] : 0;
    int j = 0;
    for (; j + 4 <= m; j += 4) {
      int s0 = __shfl(eid, j + h);
      int s1 = __shfl(eid, j + 2 + h);
      float4 v0 = *reinterpret_cast<const float4*>(&Xb[(size_t)s0 * NC + c4 * 4]);
      float4 v1 = *reinterpret_cast<const float4*>(&Xb[(size_t)s1 * NC + c4 * 4]);
      acc0.x += v0.x; acc0.y += v0.y; acc0.z += v0.z; acc0.w += v0.w;
      acc1.x += v1.x; acc1.y += v1.y; acc1.z += v1.z; acc1.w += v1.w;
    }
    if (j + 2 <= m) {
      int s0 = __shfl(eid, j + h);
      float4 v0 = *reinterpret_cast<const float4*>(&Xb[(size_t)s0 * NC + c4 * 4]);
      acc0.x += v0.x; acc0.y += v0.y; acc0.z += v0.z; acc0.w += v0.w;
      j += 2;
    }
    if (j < m) {
      int s0 = __shfl(eid, j);
      if (h == 0) {
        float4 v0 = *reinterpret_cast<const float4*>(&Xb[(size_t)s0 * NC + c4 * 4]);
        acc0.x += v0.x; acc0.y += v0.y; acc0.z += v0.z; acc0.w += v0.w;
      }
    }
  }
  acc0.x += acc1.x; acc0.y += acc1.y; acc0.z += acc1.z; acc0.w += acc1.w;
  acc0.x += __shfl_xor(acc0.x, 32);
  acc0.y += __shfl_xor(acc0.y, 32);
  acc0.z += __shfl_xor(acc0.z, 32);
  acc0.w += __shfl_xor(acc0.w, 32);
  if (h == 0) {
    unsigned p0 = (unsigned)f2bf_rne(acc0.x) | ((unsigned)f2bf_rne(acc0.y) << 16);
    unsigned p1 = (unsigned)f2bf_rne(acc0.z) | ((unsigned)f2bf_rne(acc0.w) << 16);
    *reinterpret_cast<uint2*>(&H[((size_t)b * N0 + node) * NC + c4 * 4]) = make_uint2(p0, p1);
  }
}

// ---------- fused GIN MLP: x2 = relu(relu(h0@W1+b1)@W2+b2), fused score ----------
// Block 256 thr / 4 waves; tile 128x128; T1 bounced through LDS (wave-private rows).
__global__ __launch_bounds__(256) void k_gin(const ushort_t* __restrict__ Xh,
                                             float* __restrict__ Xout,
                                             const ushort_t* __restrict__ W1t,
                                             const float* __restrict__ b1,
                                             const ushort_t* __restrict__ W2t,
                                             const float* __restrict__ b2,
                                             const float* __restrict__ pw,
                                             float* __restrict__ score, int n) {
  __shared__ ushort_t Xs[128 * 136];  // 34.8 KB
  int b = blockIdx.y;
  int r0 = blockIdx.x * 128;
  int t = threadIdx.x;
  const ushort_t* Xg = Xh + (size_t)b * N0 * NC;

  // stage h0 tile (already bf16): straight copy
#pragma unroll
  for (int p = 0; p < 8; p++) {
    int id = t + p * 256;
    int row = id >> 4, seg = id & 15;
    short8 vh = (short8)0;
    if (r0 + row < n)
      vh = *reinterpret_cast<const short8*>(&Xg[(size_t)(r0 + row) * NC + seg * 8]);
    *reinterpret_cast<short8*>(&Xs[row * 136 + seg * 8]) = vh;
  }
  __syncthreads();

  int lane = t & 63, w = t >> 6;
  int li = lane & 15, lg = lane >> 4;
  int rbase = w * 32;

  f32x4 acc[2][8];
#pragma unroll
  for (int rt = 0; rt < 2; rt++)
#pragma unroll
    for (int ct = 0; ct < 8; ct++) acc[rt][ct] = (f32x4)0.f;

  // ---- pass 1: T1 = h0 @ W1 ----
#pragma unroll
  for (int ks = 0; ks < 4; ks++) {
    short8 a0 = *reinterpret_cast<const short8*>(&Xs[(rbase + li) * 136 + ks * 32 + lg * 8]);
    short8 a1 = *reinterpret_cast<const short8*>(&Xs[(rbase + 16 + li) * 136 + ks * 32 + lg * 8]);
#pragma unroll
    for (int ct = 0; ct < 8; ct++) {
      short8 bf = *reinterpret_cast<const short8*>(&W1t[(ct * 16 + li) * NC + ks * 32 + lg * 8]);
      acc[0][ct] = __builtin_amdgcn_mfma_f32_16x16x32_bf16(a0, bf, acc[0][ct], 0, 0, 0);
      acc[1][ct] = __builtin_amdgcn_mfma_f32_16x16x32_bf16(a1, bf, acc[1][ct], 0, 0, 0);
    }
  }

  // ---- epilogue 1: relu+bias -> bf16 back into Xs (own 32 rows only) ----
  {
    float bv[8];
#pragma unroll
    for (int ct = 0; ct < 8; ct++) bv[ct] = b1[ct * 16 + li];
#pragma unroll
    for (int rt = 0; rt < 2; rt++)
#pragma unroll
      for (int ct = 0; ct < 8; ct++)
#pragma unroll
        for (int j = 0; j < 4; j++) {
          float o = fmaxf(acc[rt][ct][j] + bv[ct], 0.f);
          int row = rbase + rt * 16 + lg * 4 + j;
          Xs[row * 136 + ct * 16 + li] = f2bf_rne(o);
        }
  }

#pragma unroll
  for (int rt = 0; rt < 2; rt++)
#pragma unroll
    for (int ct = 0; ct < 8; ct++) acc[rt][ct] = (f32x4)0.f;

  // ---- pass 2: x2 = T1 @ W2 ----
#pragma unroll
  for (int ks = 0; ks < 4; ks++) {
    short8 a0 = *reinterpret_cast<const short8*>(&Xs[(rbase + li) * 136 + ks * 32 + lg * 8]);
    short8 a1 = *reinterpret_cast<const short8*>(&Xs[(rbase + 16 + li) * 136 + ks * 32 + lg * 8]);
#pragma unroll
    for (int ct = 0; ct < 8; ct++) {
      short8 bf = *reinterpret_cast<const short8*>(&W2t[(ct * 16 + li) * NC + ks * 32 + lg * 8]);
      acc[0][ct] = __builtin_amdgcn_mfma_f32_16x16x32_bf16(a0, bf, acc[0][ct], 0, 0, 0);
      acc[1][ct] = __builtin_amdgcn_mfma_f32_16x16x32_bf16(a1, bf, acc[1][ct], 0, 0, 0);
    }
  }

  // ---- epilogue 2: relu+bias, store f32, fused score ----
  float bv[8], pwv[8];
#pragma unroll
  for (int ct = 0; ct < 8; ct++) {
    bv[ct] = b2[ct * 16 + li];
    pwv[ct] = pw[ct * 16 + li];
  }
  float nrm;
  {
    float s = 0.f;
#pragma unroll
    for (int ct = 0; ct < 8; ct++) s = fmaf(pwv[ct], pwv[ct], s);
    s += __shfl_xor(s, 1); s += __shfl_xor(s, 2);
    s += __shfl_xor(s, 4); s += __shfl_xor(s, 8);
    nrm = sqrtf(s);
  }

  float* Ob = Xout + (size_t)b * N0 * NC;
#pragma unroll
  for (int rt = 0; rt < 2; rt++) {
#pragma unroll
    for (int j = 0; j < 4; j++) {
      int row = r0 + rbase + rt * 16 + lg * 4 + j;
      bool ok = row < n;
      float dot = 0.f;
#pragma unroll
      for (int ct = 0; ct < 8; ct++) {
        float o = fmaxf(acc[rt][ct][j] + bv[ct], 0.f);
        if (ok) Ob[(size_t)row * NC + ct * 16 + li] = o;
        dot = fmaf(o, pwv[ct], dot);
      }
      dot += __shfl_xor(dot, 1); dot += __shfl_xor(dot, 2);
      dot += __shfl_xor(dot, 4); dot += __shfl_xor(dot, 8);
      if (li == 0 && ok) score[b * N0 + row] = tanhf(dot / nrm);
    }
  }
}

// ---------- top-k threshold via 4-pass radix select ----------
__global__ __launch_bounds__(1024) void k_select(const float* __restrict__ score,
                                                 unsigned* __restrict__ vstar, int* __restrict__ quota,
                                                 int n, int k) {
  __shared__ int hist[256];
  __shared__ unsigned s_pref;
  __shared__ int s_r, s_gt;
  int b = blockIdx.x, t = threadIdx.x, lane = t & 63;
  if (t == 0) { s_pref = 0u; s_r = k; s_gt = 0; }
  __syncthreads();
  for (int pass = 0; pass < 4; ++pass) {
    int shift = 24 - pass * 8;
    if (t < 256) hist[t] = 0;
    __syncthreads();
    unsigned pref = s_pref;
    unsigned pmask = (pass == 0) ? 0u : (0xFFFFFFFFu << (shift + 8));
    for (int j0 = 0; j0 < n; j0 += 1024) {
      int j = j0 + t;
      unsigned key = (j < n) ? mono_u(score[b * N0 + j]) : 0u;
      unsigned d = (key >> shift) & 255;
      int contrib = (j < n) && ((key & pmask) == pref);
      unsigned long long bal = __ballot(contrib);
      if (bal == 0) continue;
      int fl = __ffsll((long long)bal) - 1;
      unsigned dref = __shfl(d, fl);
      if (__all(!contrib || d == dref)) {
        if (lane == fl) atomicAdd(&hist[dref], (int)__popcll(bal));
      } else if (contrib) {
        atomicAdd(&hist[d], 1);
      }
    }
    __syncthreads();
    if (t == 0) {
      int r = s_r, acc = 0, d = 255;
      for (; d >= 0; --d) {
        if (acc + hist[d] >= r) break;
        acc += hist[d];
      }
      s_gt += acc;
      s_r = r - acc;
      s_pref = pref | ((unsigned)d << shift);
    }
    __syncthreads();
  }
  if (t == 0) {
    vstar[b] = s_pref;
    quota[b] = k - s_gt;
  }
}

// ---------- map phase 1: per-1024-chunk gt/tie counts ----------
__global__ __launch_bounds__(1024) void k_map_cnt(const float* __restrict__ score,
                                                  const unsigned* __restrict__ vstar,
                                                  int* __restrict__ gcnt, int* __restrict__ tcnt, int n) {
  __shared__ int wg[16], wt[16];
  int b = blockIdx.y, chunk = blockIdx.x, t = threadIdx.x;
  int lane = t & 63, wid = t >> 6;
  int j = chunk * 1024 + t;
  unsigned vs = vstar[b];
  unsigned key = (j < n) ? mono_u(score[b * N0 + j]) : 0u;
  int gt = (j < n) && (key > vs);
  int tie = (j < n) && (key == vs);
  unsigned long long bg = __ballot(gt), bt = __ballot(tie);
  if (lane == 0) { wg[wid] = (int)__popcll(bg); wt[wid] = (int)__popcll(bt); }
  __syncthreads();
  if (t == 0) {
    int g = 0, tt = 0;
    for (int w = 0; w < 16; w++) { g += wg[w]; tt += wt[w]; }
    gcnt[b * 16 + chunk] = g;
    tcnt[b * 16 + chunk] = tt;
  }
}

// ---------- map phase 2: assign new ids, jax.lax.top_k tie semantics ----------
__global__ __launch_bounds__(1024) void k_map_wr(const float* __restrict__ score,
                                                 const unsigned* __restrict__ vstar,
                                                 const int* __restrict__ quota,
                                                 const int* __restrict__ gcnt, const int* __restrict__ tcnt,
                                                 int* __restrict__ mp, int n) {
  __shared__ int wg[16], wt[16];
  __shared__ int s_gb, s_tb;
  int b = blockIdx.y, chunk = blockIdx.x, t = threadIdx.x;
  int lane = t & 63, wid = t >> 6;
  if (t == 0) {
    int gb = 0, tb = 0;
    for (int c = 0; c < chunk; c++) { gb += gcnt[b * 16 + c]; tb += tcnt[b * 16 + c]; }
    s_gb = gb; s_tb = tb;
  }
  int j = chunk * 1024 + t;
  unsigned vs = vstar[b];
  int q = quota[b];
  unsigned key = (j < n) ? mono_u(score[b * N0 + j]) : 0u;
  int gt = (j < n) && (key > vs);
  int tie = (j < n) && (key == vs);
  unsigned long long bg = __ballot(gt), bt = __ballot(tie);
  if (lane == 0) { wg[wid] = (int)__popcll(bg); wt[wid] = (int)__popcll(bt); }
  __syncthreads();
  if (j >= n) return;
  unsigned long long ltm = (lane == 63) ? ~0ull >> 1 : ((1ull << lane) - 1);
  int gloc = (int)__popcll(bg & ltm);
  int tloc = (int)__popcll(bt & ltm);
  for (int w = 0; w < 16; w++) {
    if (w < wid) { gloc += wg[w]; tloc += wt[w]; }
  }
  int tie_rank = s_tb + tloc;
  int sel = gt || (tie && tie_rank < q);
  int pos = s_gb + gloc + min(tie_rank, q);
  mp[b * N0 + j] = sel ? pos : -1;
}

// ---------- compact selected rows, scaled by score ----------
__global__ void k_compact(const float* __restrict__ Xin, float* __restrict__ Xout,
                          const int* __restrict__ mp, const float* __restrict__ score, int n) {
  int lane = threadIdx.x & 63, wid = threadIdx.x >> 6;
  int node = blockIdx.x * 4 + wid;
  int b = blockIdx.y;
  if (node >= n) return;
  int m = mp[b * N0 + node];
  if (m < 0) return;
  float val = score[b * N0 + node];
  float2 v = *reinterpret_cast<const float2*>(&Xin[((size_t)b * N0 + node) * NC + lane * 2]);
  v.x *= val; v.y *= val;
  *reinterpret_cast<float2*>(&Xout[((size_t)b * N0 + m) * NC + lane * 2]) = v;
}

// ---------- remap edges in place; count next-depth in-degrees ----------
__global__ void k_remap(int* __restrict__ srcw, int* __restrict__ dstw,
                        const int* __restrict__ mp, int* __restrict__ cnt) {
  int tot = NB * NE;
  int tid = blockIdx.x * blockDim.x + threadIdx.x;
  int stride = gridDim.x * blockDim.x;
  for (int i = tid; i < tot; i += stride) {
    int d = dstw[i];
    if (d < 0) continue;
    int b = i / NE;
    int s = srcw[i];
    int ns = mp[b * N0 + s], nd = mp[b * N0 + d];
    if (ns >= 0 && nd >= 0) {
      srcw[i] = ns;
      dstw[i] = nd;
      atomicAdd(&cnt[b * N0 + nd], 1);
    } else {
      srcw[i] = 0;
      dstw[i] = -1;
    }
  }
}

// ---------- readout: per-channel max + sum into per-depth buffers ----------
__global__ void k_readout(const float* __restrict__ X, int* __restrict__ maxbuf,
                          float* __restrict__ sumbuf, int n) {
  __shared__ float smx[128], ssm[128];
  int b = blockIdx.y;
  int nchunk = gridDim.x;
  int rows = (n + nchunk - 1) / nchunk;
  int lo = blockIdx.x * rows;
  int hi = min(lo + rows, n);
  int c = threadIdx.x & 127, h = threadIdx.x >> 7;
  float mx = -INFINITY, sm = 0.f;
  for (int r = lo + h; r < hi; r += 2) {
    float v = X[((size_t)b * N0 + r) * NC + c];
    mx = fmaxf(mx, v);
    sm += v;
  }
  if (h) { smx[c] = mx; ssm[c] = sm; }
  __syncthreads();
  if (!h) {
    mx = fmaxf(mx, smx[c]);
    sm += ssm[c];
    atomicMax(&maxbuf[b * NC + c], f2ikey(mx));
    atomicAdd(&sumbuf[b * NC + c], sm);
  }
}

// ---------- predictor MLP (folds readout-sum across depths) ----------
__global__ __launch_bounds__(256) void k_pred(const int* __restrict__ maxbuf,
                                              const float* __restrict__ sumbuf,
                                              const float* __restrict__ q1w, const float* __restrict__ q1b,
                                              const float* __restrict__ q2w, const float* __restrict__ q2b,
                                              const float* __restrict__ q3w, const float* __restrict__ q3b,
                                              float* __restrict__ out) {
  __shared__ float rr[256], h1[128], h2[64];
  int b = blockIdx.x, t = threadIdx.x;
  const float kdiv[4] = {13108.f, 10487.f, 8390.f, 6712.f};
  float acc = 0.f;
#pragma unroll
  for (int d = 0; d < 4; d++) {
    if (t < 128) acc += ikey2f(maxbuf[d * NB * NC + b * NC + t]);
    else acc += sumbuf[d * NB * NC + b * NC + (t - 128)] / kdiv[d];
  }
  rr[t] = acc;
  __syncthreads();
  if (t < 128) {
    float s = q1b[t];
    for (int j = 0; j < 256; j++) s = fmaf(rr[j], q1w[j * 128 + t], s);
    h1[t] = fmaxf(s, 0.f);
  }
  __syncthreads();
  if (t < 64) {
    float s = q2b[t];
    for (int j = 0; j < 128; j++) s = fmaf(h1[j], q2w[j * 64 + t], s);
    h2[t] = fmaxf(s, 0.f);
  }
  __syncthreads();
  if (t < 2) {
    float s = q3b[t];
    for (int j = 0; j < 64; j++) s = fmaf(h2[j], q3w[j * 2 + t], s);
    out[b * 2 + t] = s;
  }
}

// ---------- host orchestration ----------
extern "C" void kernel_launch(void* const* d_in, const int* in_sizes, int n_in,
                              void* d_out, int out_size, void* d_ws, size_t ws_size,
                              hipStream_t stream) {
  const float* x = (const float*)d_in[0];
  const int* src = (const int*)d_in[1];
  const int* dst = (const int*)d_in[2];
  const float* q1w = (const float*)d_in[23];
  const float* q1b = (const float*)d_in[24];
  const float* q2w = (const float*)d_in[25];
  const float* q2b = (const float*)d_in[26];
  const float* q3w = (const float*)d_in[27];
  const float* q3b = (const float*)d_in[28];

  char* p = (char*)d_ws;
  auto alloc = [&](size_t bytes) {
    char* q = p;
    p += (bytes + 255) & ~(size_t)255;
    return q;
  };
  float* Xa = (float*)alloc((size_t)NB * N0 * NC * 4);       // pooled x (f32)
  float* Xb = (float*)alloc((size_t)NB * N0 * NC * 4);       // x2 (f32)
  ushort_t* Xh = (ushort_t*)alloc((size_t)NB * N0 * NC * 2); // h0 (bf16)
  int* srcw = (int*)alloc((size_t)NB * NE * 4);
  int* dstw = (int*)alloc((size_t)NB * NE * 4);
  int* elist = (int*)alloc((size_t)NB * NE * 4);
  int* cnt = (int*)alloc((size_t)NB * N0 * 4);
  int* offs = (int*)alloc((size_t)NB * N0 * 4);
  int* cursor = (int*)alloc((size_t)NB * N0 * 4);
  float* score = (float*)alloc((size_t)NB * N0 * 4);
  int* mp = (int*)alloc((size_t)NB * N0 * 4);
  unsigned* vstar = (unsigned*)alloc(256);
  int* quota = (int*)alloc(256);
  int* gcnt = (int*)alloc(NB * 16 * 4);
  int* tcnt = (int*)alloc(NB * 16 * 4);
  int* maxbuf = (int*)alloc(4 * NB * NC * 4);
  float* sumbuf = (float*)alloc(4 * NB * NC * 4);
  ushort_t* Wt_all = (ushort_t*)alloc((size_t)8 * NC * NC * 2);

  hipMemsetAsync(cnt, 0, (size_t)NB * N0 * 4, stream);
  k_init<<<2048, 256, 0, stream>>>(src, dst, srcw, dstw, cnt, maxbuf, sumbuf);
  for (int i = 0; i < 4; i++) {
    k_wprep<<<64, 256, 0, stream>>>((const float*)d_in[3 + i * 5 + 0], Wt_all + (size_t)(2 * i) * NC * NC);
    k_wprep<<<64, 256, 0, stream>>>((const float*)d_in[3 + i * 5 + 2], Wt_all + (size_t)(2 * i + 1) * NC * NC);
  }

  static const int NSv[4] = {16384, 13108, 10487, 8390};
  static const int KSv[4] = {13108, 10487, 8390, 6712};
  for (int i = 0; i < 4; i++) {
    int n = NSv[i], k = KSv[i];
    const float* b1 = (const float*)d_in[3 + i * 5 + 1];
    const float* b2 = (const float*)d_in[3 + i * 5 + 3];
    const float* pw = (const float*)d_in[3 + i * 5 + 4];
    const ushort_t* w1t = Wt_all + (size_t)(2 * i) * NC * NC;
    const ushort_t* w2t = Wt_all + (size_t)(2 * i + 1) * NC * NC;
    const float* cur = (i == 0) ? x : Xa;

    k_scan<<<NB, 1024, 0, stream>>>(cnt, offs, cursor);          // zeroes cnt
    k_fill<<<1024, 256, 0, stream>>>(srcw, dstw, cursor, elist); // cursor -> end offsets

    k_gather<<<((n + 3) / 4) * 8, 256, 0, stream>>>(cur, Xh, offs, cursor, elist, n);

    dim3 gg((n + 127) / 128, NB);
    k_gin<<<gg, 256, 0, stream>>>(Xh, Xb, w1t, b1, w2t, b2, pw, score, n);

    k_select<<<NB, 1024, 0, stream>>>(score, vstar, quota, n, k);
    dim3 gm(16, NB);
    k_map_cnt<<<gm, 1024, 0, stream>>>(score, vstar, gcnt, tcnt, n);
    k_map_wr<<<gm, 1024, 0, stream>>>(score, vstar, quota, gcnt, tcnt, mp, n);

    dim3 gs((n + 3) / 4, NB);
    k_compact<<<gs, 256, 0, stream>>>(Xb, Xa, mp, score, n);     // Xa = pooled x
    k_remap<<<1024, 256, 0, stream>>>(srcw, dstw, mp, cnt);      // counts next depth

    dim3 gr(32, NB);
    k_readout<<<gr, 256, 0, stream>>>(Xa, maxbuf + i * NB * NC, sumbuf + i * NB * NC, k);
  }

  k_pred<<<NB, 256, 0, stream>>>(maxbuf, sumbuf, q1w, q1b, q2w, q2b, q3w, q3b, (float*)d_out);
}

// Round 6
// 979.644 us; speedup vs baseline: 3.8891x; 1.0949x over previous
//
#include <hip/hip_runtime.h>
#include <math.h>

#define NB 8
#define N0 16384
#define NC 128
#define NE 98304

typedef unsigned short ushort_t;
using short8 = __attribute__((ext_vector_type(8))) short;
using f32x4 = __attribute__((ext_vector_type(4))) float;

// ---------- helpers ----------
__device__ __forceinline__ unsigned mono_u(float f) {
  unsigned u = __float_as_uint(f);
  return (u & 0x80000000u) ? ~u : (u | 0x80000000u);
}
__device__ __forceinline__ int f2ikey(float f) {
  int i = __float_as_int(f);
  return (i >= 0) ? i : (i ^ 0x7fffffff);
}
__device__ __forceinline__ float ikey2f(int k) {
  return __int_as_float(k >= 0 ? k : (k ^ 0x7fffffff));
}
__device__ __forceinline__ ushort_t f2bf_rne(float f) {
  unsigned u = __float_as_uint(f);
  unsigned r = u + 0x7fffu + ((u >> 16) & 1u);
  return (ushort_t)(r >> 16);
}

// ---------- init: copy edges, depth-0 in-degree count, init readout buffers ----------
// cnt must be pre-zeroed (hipMemsetAsync) before this kernel.
__global__ void k_init(const int* __restrict__ src, const int* __restrict__ dst,
                       int* __restrict__ srcw, int* __restrict__ dstw,
                       int* __restrict__ cnt, int* __restrict__ maxbuf, float* __restrict__ sumbuf) {
  int stride = gridDim.x * blockDim.x;
  int i = blockIdx.x * blockDim.x + threadIdx.x;
  for (int j = i; j < NB * NE; j += stride) {
    int d = dst[j];
    srcw[j] = src[j];
    dstw[j] = d;
    atomicAdd(&cnt[(j / NE) * N0 + d], 1);
  }
  for (int j = i; j < 4 * NB * NC; j += stride) {
    maxbuf[j] = (int)0x80000000;
    sumbuf[j] = 0.f;
  }
}

// ---------- weight prep: W[k][c] f32 -> Wt[c][k] bf16 ----------
__global__ void k_wprep(const float* __restrict__ W, ushort_t* __restrict__ Wt) {
  int id = blockIdx.x * blockDim.x + threadIdx.x;
  if (id >= NC * NC) return;
  int k = id >> 7, c = id & 127;
  Wt[c * NC + k] = f2bf_rne(W[id]);
}

// ---------- CSR build: per-graph exclusive scan; zeroes cnt for reuse ----------
__global__ __launch_bounds__(1024) void k_scan(int* __restrict__ cnt,
                                               int* __restrict__ offs, int* __restrict__ cursor) {
  __shared__ int ws[1024];
  int b = blockIdx.x, t = threadIdx.x;
  int base = b * N0 + t * 16;
  int loc[16];
  int s = 0;
#pragma unroll
  for (int j = 0; j < 16; j++) { loc[j] = cnt[base + j]; s += loc[j]; cnt[base + j] = 0; }
  ws[t] = s;
  __syncthreads();
  for (int o = 1; o < 1024; o <<= 1) {
    int v = (t >= o) ? ws[t - o] : 0;
    __syncthreads();
    ws[t] += v;
    __syncthreads();
  }
  int excl = ws[t] - s;
#pragma unroll
  for (int j = 0; j < 16; j++) {
    offs[base + j] = excl;
    cursor[base + j] = excl;
    excl += loc[j];
  }
}

// ---------- CSR build: fill edge list; cursor ends as end-offset ----------
__global__ void k_fill(const int* __restrict__ srcw, const int* __restrict__ dstw,
                       int* __restrict__ cursor, int* __restrict__ elist) {
  int tot = NB * NE;
  for (int i = blockIdx.x * blockDim.x + threadIdx.x; i < tot; i += gridDim.x * blockDim.x) {
    int d = dstw[i];
    if (d < 0) continue;
    int b = i / NE;
    int pos = atomicAdd(&cursor[b * N0 + d], 1);
    elist[b * NE + pos] = srcw[i];
  }
}

// ---------- gather: H[node] = bf16( X[node] + sum_{src} X[src] ) ----------
// 1D grid, graph = blockIdx.x & 7 -> XCD-pinned (per-XCD L2 holds one graph).
__global__ void k_gather(const float* __restrict__ X, ushort_t* __restrict__ H,
                         const int* __restrict__ offs, const int* __restrict__ cend,
                         const int* __restrict__ elist, int n) {
  int b = blockIdx.x & 7;
  int chunk = blockIdx.x >> 3;
  int lane = threadIdx.x & 63, wid = threadIdx.x >> 6;
  int node = chunk * 4 + wid;
  if (node >= n) return;
  int off = offs[b * N0 + node];
  int deg = cend[b * N0 + node] - off;
  int h = lane >> 5, c4 = lane & 31;
  const float* Xb = X + (size_t)b * N0 * NC;

  float4 acc0 = make_float4(0.f, 0.f, 0.f, 0.f);
  float4 acc1 = make_float4(0.f, 0.f, 0.f, 0.f);
  if (h == 0) acc0 = *reinterpret_cast<const float4*>(&Xb[(size_t)node * NC + c4 * 4]);

  for (int base = 0; base < deg; base += 64) {
    int m = min(64, deg - base);
    int eid = (lane < m) ? elist[b * NE + off + base + lane] : 0;
    int j = 0;
    for (; j + 4 <= m; j += 4) {
      int s0 = __shfl(eid, j + h);
      int s1 = __shfl(eid, j + 2 + h);
      float4 v0 = *reinterpret_cast<const float4*>(&Xb[(size_t)s0 * NC + c4 * 4]);
      float4 v1 = *reinterpret_cast<const float4*>(&Xb[(size_t)s1 * NC + c4 * 4]);
      acc0.x += v0.x; acc0.y += v0.y; acc0.z += v0.z; acc0.w += v0.w;
      acc1.x += v1.x; acc1.y += v1.y; acc1.z += v1.z; acc1.w += v1.w;
    }
    if (j + 2 <= m) {
      int s0 = __shfl(eid, j + h);
      float4 v0 = *reinterpret_cast<const float4*>(&Xb[(size_t)s0 * NC + c4 * 4]);
      acc0.x += v0.x; acc0.y += v0.y; acc0.z += v0.z; acc0.w += v0.w;
      j += 2;
    }
    if (j < m) {
      int s0 = __shfl(eid, j);
      if (h == 0) {
        float4 v0 = *reinterpret_cast<const float4*>(&Xb[(size_t)s0 * NC + c4 * 4]);
        acc0.x += v0.x; acc0.y += v0.y; acc0.z += v0.z; acc0.w += v0.w;
      }
    }
  }
  acc0.x += acc1.x; acc0.y += acc1.y; acc0.z += acc1.z; acc0.w += acc1.w;
  acc0.x += __shfl_xor(acc0.x, 32);
  acc0.y += __shfl_xor(acc0.y, 32);
  acc0.z += __shfl_xor(acc0.z, 32);
  acc0.w += __shfl_xor(acc0.w, 32);
  if (h == 0) {
    unsigned p0 = (unsigned)f2bf_rne(acc0.x) | ((unsigned)f2bf_rne(acc0.y) << 16);
    unsigned p1 = (unsigned)f2bf_rne(acc0.z) | ((unsigned)f2bf_rne(acc0.w) << 16);
    *reinterpret_cast<uint2*>(&H[((size_t)b * N0 + node) * NC + c4 * 4]) = make_uint2(p0, p1);
  }
}

// ---------- fused GIN MLP: x2 = relu(relu(h0@W1+b1)@W2+b2), fused score ----------
// Block 256 thr / 4 waves; tile 128x128. SWAPPED mfma operands: D[lane&15 = X row,
// reg = 4 consecutive W cols] -> float4 stores. W staged in LDS (re-staged W1->W2).
// 1D grid, graph = blockIdx.x & 7 (XCD-pinned).
__global__ __launch_bounds__(256) void k_gin(const ushort_t* __restrict__ Xh,
                                             float* __restrict__ Xout,
                                             const ushort_t* __restrict__ W1t,
                                             const float* __restrict__ b1,
                                             const ushort_t* __restrict__ W2t,
                                             const float* __restrict__ b2,
                                             const float* __restrict__ pw,
                                             float* __restrict__ score, int n) {
  __shared__ ushort_t Ts[128 * 136];   // X tile, then T1 (wave-private rows)
  __shared__ ushort_t Wsh[128 * 136];  // W1, then W2
  int b = blockIdx.x & 7;
  int r0 = (blockIdx.x >> 3) * 128;
  int t = threadIdx.x;
  const ushort_t* Xg = Xh + (size_t)b * N0 * NC;

  // stage X tile (bf16 copy) + W1, padded stride 136
#pragma unroll
  for (int p = 0; p < 8; p++) {
    int id = t + p * 256;
    int row = id >> 4, seg = id & 15;
    short8 vh = (short8)0;
    if (r0 + row < n)
      vh = *reinterpret_cast<const short8*>(&Xg[(size_t)(r0 + row) * NC + seg * 8]);
    *reinterpret_cast<short8*>(&Ts[row * 136 + seg * 8]) = vh;
    *reinterpret_cast<short8*>(&Wsh[row * 136 + seg * 8]) =
        *reinterpret_cast<const short8*>(&W1t[row * NC + seg * 8]);
  }
  __syncthreads();

  int lane = t & 63, w = t >> 6;
  int li = lane & 15, lg = lane >> 4;
  int rbase = w * 32;

  f32x4 acc[2][8];
#pragma unroll
  for (int rt = 0; rt < 2; rt++)
#pragma unroll
    for (int ct = 0; ct < 8; ct++) acc[rt][ct] = (f32x4)0.f;

  // ---- pass 1: T1 = h0 @ W1 (A = W-frag, B = X-frag -> transposed D) ----
#pragma unroll
  for (int ks = 0; ks < 4; ks++) {
    short8 x0 = *reinterpret_cast<const short8*>(&Ts[(rbase + li) * 136 + ks * 32 + lg * 8]);
    short8 x1 = *reinterpret_cast<const short8*>(&Ts[(rbase + 16 + li) * 136 + ks * 32 + lg * 8]);
#pragma unroll
    for (int ct = 0; ct < 8; ct++) {
      short8 wf = *reinterpret_cast<const short8*>(&Wsh[(ct * 16 + li) * 136 + ks * 32 + lg * 8]);
      acc[0][ct] = __builtin_amdgcn_mfma_f32_16x16x32_bf16(wf, x0, acc[0][ct], 0, 0, 0);
      acc[1][ct] = __builtin_amdgcn_mfma_f32_16x16x32_bf16(wf, x1, acc[1][ct], 0, 0, 0);
    }
  }

  // ---- epilogue 1: relu+bias -> bf16 into Ts (own rows; b64 writes) ----
#pragma unroll
  for (int rt = 0; rt < 2; rt++) {
    int row = rbase + rt * 16 + li;
#pragma unroll
    for (int ct = 0; ct < 8; ct++) {
      float4 bq = *reinterpret_cast<const float4*>(&b1[ct * 16 + lg * 4]);
      float o0 = fmaxf(acc[rt][ct][0] + bq.x, 0.f);
      float o1 = fmaxf(acc[rt][ct][1] + bq.y, 0.f);
      float o2 = fmaxf(acc[rt][ct][2] + bq.z, 0.f);
      float o3 = fmaxf(acc[rt][ct][3] + bq.w, 0.f);
      unsigned p0 = (unsigned)f2bf_rne(o0) | ((unsigned)f2bf_rne(o1) << 16);
      unsigned p1 = (unsigned)f2bf_rne(o2) | ((unsigned)f2bf_rne(o3) << 16);
      *reinterpret_cast<uint2*>(&Ts[row * 136 + ct * 16 + lg * 4]) = make_uint2(p0, p1);
    }
  }

  // ---- re-stage W2 over W1 (needs all waves done with Wsh) ----
  __syncthreads();
#pragma unroll
  for (int p = 0; p < 8; p++) {
    int id = t + p * 256;
    int row = id >> 4, seg = id & 15;
    *reinterpret_cast<short8*>(&Wsh[row * 136 + seg * 8]) =
        *reinterpret_cast<const short8*>(&W2t[row * NC + seg * 8]);
  }
  __syncthreads();

#pragma unroll
  for (int rt = 0; rt < 2; rt++)
#pragma unroll
    for (int ct = 0; ct < 8; ct++) acc[rt][ct] = (f32x4)0.f;

  // ---- pass 2: x2 = T1 @ W2 ----
#pragma unroll
  for (int ks = 0; ks < 4; ks++) {
    short8 x0 = *reinterpret_cast<const short8*>(&Ts[(rbase + li) * 136 + ks * 32 + lg * 8]);
    short8 x1 = *reinterpret_cast<const short8*>(&Ts[(rbase + 16 + li) * 136 + ks * 32 + lg * 8]);
#pragma unroll
    for (int ct = 0; ct < 8; ct++) {
      short8 wf = *reinterpret_cast<const short8*>(&Wsh[(ct * 16 + li) * 136 + ks * 32 + lg * 8]);
      acc[0][ct] = __builtin_amdgcn_mfma_f32_16x16x32_bf16(wf, x0, acc[0][ct], 0, 0, 0);
      acc[1][ct] = __builtin_amdgcn_mfma_f32_16x16x32_bf16(wf, x1, acc[1][ct], 0, 0, 0);
    }
  }

  // ---- epilogue 2: relu+bias, float4 stores, fused score ----
  f32x4 pq[8];
  float psum = 0.f;
#pragma unroll
  for (int ct = 0; ct < 8; ct++) {
    pq[ct] = *reinterpret_cast<const f32x4*>(&pw[ct * 16 + lg * 4]);
    psum = fmaf(pq[ct][0], pq[ct][0], psum);
    psum = fmaf(pq[ct][1], pq[ct][1], psum);
    psum = fmaf(pq[ct][2], pq[ct][2], psum);
    psum = fmaf(pq[ct][3], pq[ct][3], psum);
  }
  psum += __shfl_xor(psum, 16);
  psum += __shfl_xor(psum, 32);
  float nrm = sqrtf(psum);

  float* Ob = Xout + (size_t)b * N0 * NC;
#pragma unroll
  for (int rt = 0; rt < 2; rt++) {
    int row = r0 + rbase + rt * 16 + li;
    bool ok = row < n;
    float dot = 0.f;
#pragma unroll
    for (int ct = 0; ct < 8; ct++) {
      float4 bq = *reinterpret_cast<const float4*>(&b2[ct * 16 + lg * 4]);
      float4 o;
      o.x = fmaxf(acc[rt][ct][0] + bq.x, 0.f);
      o.y = fmaxf(acc[rt][ct][1] + bq.y, 0.f);
      o.z = fmaxf(acc[rt][ct][2] + bq.z, 0.f);
      o.w = fmaxf(acc[rt][ct][3] + bq.w, 0.f);
      dot = fmaf(o.x, pq[ct][0], dot);
      dot = fmaf(o.y, pq[ct][1], dot);
      dot = fmaf(o.z, pq[ct][2], dot);
      dot = fmaf(o.w, pq[ct][3], dot);
      if (ok) *reinterpret_cast<float4*>(&Ob[(size_t)row * NC + ct * 16 + lg * 4]) = o;
    }
    dot += __shfl_xor(dot, 16);
    dot += __shfl_xor(dot, 32);
    if (lg == 0 && ok) score[b * N0 + row] = tanhf(dot / nrm);
  }
}

// ---------- top-k threshold via 4-pass radix select ----------
__global__ __launch_bounds__(1024) void k_select(const float* __restrict__ score,
                                                 unsigned* __restrict__ vstar, int* __restrict__ quota,
                                                 int n, int k) {
  __shared__ int hist[256];
  __shared__ unsigned s_pref;
  __shared__ int s_r, s_gt;
  int b = blockIdx.x, t = threadIdx.x, lane = t & 63;
  if (t == 0) { s_pref = 0u; s_r = k; s_gt = 0; }
  __syncthreads();
  for (int pass = 0; pass < 4; ++pass) {
    int shift = 24 - pass * 8;
    if (t < 256) hist[t] = 0;
    __syncthreads();
    unsigned pref = s_pref;
    unsigned pmask = (pass == 0) ? 0u : (0xFFFFFFFFu << (shift + 8));
    for (int j0 = 0; j0 < n; j0 += 1024) {
      int j = j0 + t;
      unsigned key = (j < n) ? mono_u(score[b * N0 + j]) : 0u;
      unsigned d = (key >> shift) & 255;
      int contrib = (j < n) && ((key & pmask) == pref);
      unsigned long long bal = __ballot(contrib);
      if (bal == 0) continue;
      int fl = __ffsll((long long)bal) - 1;
      unsigned dref = __shfl(d, fl);
      if (__all(!contrib || d == dref)) {
        if (lane == fl) atomicAdd(&hist[dref], (int)__popcll(bal));
      } else if (contrib) {
        atomicAdd(&hist[d], 1);
      }
    }
    __syncthreads();
    if (t == 0) {
      int r = s_r, acc = 0, d = 255;
      for (; d >= 0; --d) {
        if (acc + hist[d] >= r) break;
        acc += hist[d];
      }
      s_gt += acc;
      s_r = r - acc;
      s_pref = pref | ((unsigned)d << shift);
    }
    __syncthreads();
  }
  if (t == 0) {
    vstar[b] = s_pref;
    quota[b] = k - s_gt;
  }
}

// ---------- map phase 1: per-1024-chunk gt/tie counts ----------
__global__ __launch_bounds__(1024) void k_map_cnt(const float* __restrict__ score,
                                                  const unsigned* __restrict__ vstar,
                                                  int* __restrict__ gcnt, int* __restrict__ tcnt, int n) {
  __shared__ int wg[16], wt[16];
  int b = blockIdx.y, chunk = blockIdx.x, t = threadIdx.x;
  int lane = t & 63, wid = t >> 6;
  int j = chunk * 1024 + t;
  unsigned vs = vstar[b];
  unsigned key = (j < n) ? mono_u(score[b * N0 + j]) : 0u;
  int gt = (j < n) && (key > vs);
  int tie = (j < n) && (key == vs);
  unsigned long long bg = __ballot(gt), bt = __ballot(tie);
  if (lane == 0) { wg[wid] = (int)__popcll(bg); wt[wid] = (int)__popcll(bt); }
  __syncthreads();
  if (t == 0) {
    int g = 0, tt = 0;
    for (int w = 0; w < 16; w++) { g += wg[w]; tt += wt[w]; }
    gcnt[b * 16 + chunk] = g;
    tcnt[b * 16 + chunk] = tt;
  }
}

// ---------- map phase 2: assign new ids, jax.lax.top_k tie semantics ----------
__global__ __launch_bounds__(1024) void k_map_wr(const float* __restrict__ score,
                                                 const unsigned* __restrict__ vstar,
                                                 const int* __restrict__ quota,
                                                 const int* __restrict__ gcnt, const int* __restrict__ tcnt,
                                                 int* __restrict__ mp, int n) {
  __shared__ int wg[16], wt[16];
  __shared__ int s_gb, s_tb;
  int b = blockIdx.y, chunk = blockIdx.x, t = threadIdx.x;
  int lane = t & 63, wid = t >> 6;
  if (t == 0) {
    int gb = 0, tb = 0;
    for (int c = 0; c < chunk; c++) { gb += gcnt[b * 16 + c]; tb += tcnt[b * 16 + c]; }
    s_gb = gb; s_tb = tb;
  }
  int j = chunk * 1024 + t;
  unsigned vs = vstar[b];
  int q = quota[b];
  unsigned key = (j < n) ? mono_u(score[b * N0 + j]) : 0u;
  int gt = (j < n) && (key > vs);
  int tie = (j < n) && (key == vs);
  unsigned long long bg = __ballot(gt), bt = __ballot(tie);
  if (lane == 0) { wg[wid] = (int)__popcll(bg); wt[wid] = (int)__popcll(bt); }
  __syncthreads();
  if (j >= n) return;
  unsigned long long ltm = (lane == 63) ? ~0ull >> 1 : ((1ull << lane) - 1);
  int gloc = (int)__popcll(bg & ltm);
  int tloc = (int)__popcll(bt & ltm);
  for (int w = 0; w < 16; w++) {
    if (w < wid) { gloc += wg[w]; tloc += wt[w]; }
  }
  int tie_rank = s_tb + tloc;
  int sel = gt || (tie && tie_rank < q);
  int pos = s_gb + gloc + min(tie_rank, q);
  mp[b * N0 + j] = sel ? pos : -1;
}

// ---------- compact selected rows, scaled by score ----------
__global__ void k_compact(const float* __restrict__ Xin, float* __restrict__ Xout,
                          const int* __restrict__ mp, const float* __restrict__ score, int n) {
  int lane = threadIdx.x & 63, wid = threadIdx.x >> 6;
  int node = blockIdx.x * 4 + wid;
  int b = blockIdx.y;
  if (node >= n) return;
  int m = mp[b * N0 + node];
  if (m < 0) return;
  float val = score[b * N0 + node];
  float2 v = *reinterpret_cast<const float2*>(&Xin[((size_t)b * N0 + node) * NC + lane * 2]);
  v.x *= val; v.y *= val;
  *reinterpret_cast<float2*>(&Xout[((size_t)b * N0 + m) * NC + lane * 2]) = v;
}

// ---------- remap edges in place; count next-depth in-degrees ----------
__global__ void k_remap(int* __restrict__ srcw, int* __restrict__ dstw,
                        const int* __restrict__ mp, int* __restrict__ cnt) {
  int tot = NB * NE;
  int tid = blockIdx.x * blockDim.x + threadIdx.x;
  int stride = gridDim.x * blockDim.x;
  for (int i = tid; i < tot; i += stride) {
    int d = dstw[i];
    if (d < 0) continue;
    int b = i / NE;
    int s = srcw[i];
    int ns = mp[b * N0 + s], nd = mp[b * N0 + d];
    if (ns >= 0 && nd >= 0) {
      srcw[i] = ns;
      dstw[i] = nd;
      atomicAdd(&cnt[b * N0 + nd], 1);
    } else {
      srcw[i] = 0;
      dstw[i] = -1;
    }
  }
}

// ---------- readout: per-channel max + sum into per-depth buffers ----------
__global__ void k_readout(const float* __restrict__ X, int* __restrict__ maxbuf,
                          float* __restrict__ sumbuf, int n) {
  __shared__ float smx[128], ssm[128];
  int b = blockIdx.y;
  int nchunk = gridDim.x;
  int rows = (n + nchunk - 1) / nchunk;
  int lo = blockIdx.x * rows;
  int hi = min(lo + rows, n);
  int c = threadIdx.x & 127, h = threadIdx.x >> 7;
  float mx = -INFINITY, sm = 0.f;
  for (int r = lo + h; r < hi; r += 2) {
    float v = X[((size_t)b * N0 + r) * NC + c];
    mx = fmaxf(mx, v);
    sm += v;
  }
  if (h) { smx[c] = mx; ssm[c] = sm; }
  __syncthreads();
  if (!h) {
    mx = fmaxf(mx, smx[c]);
    sm += ssm[c];
    atomicMax(&maxbuf[b * NC + c], f2ikey(mx));
    atomicAdd(&sumbuf[b * NC + c], sm);
  }
}

// ---------- predictor MLP (folds readout-sum across depths) ----------
__global__ __launch_bounds__(256) void k_pred(const int* __restrict__ maxbuf,
                                              const float* __restrict__ sumbuf,
                                              const float* __restrict__ q1w, const float* __restrict__ q1b,
                                              const float* __restrict__ q2w, const float* __restrict__ q2b,
                                              const float* __restrict__ q3w, const float* __restrict__ q3b,
                                              float* __restrict__ out) {
  __shared__ float rr[256], h1[128], h2[64];
  int b = blockIdx.x, t = threadIdx.x;
  const float kdiv[4] = {13108.f, 10487.f, 8390.f, 6712.f};
  float acc = 0.f;
#pragma unroll
  for (int d = 0; d < 4; d++) {
    if (t < 128) acc += ikey2f(maxbuf[d * NB * NC + b * NC + t]);
    else acc += sumbuf[d * NB * NC + b * NC + (t - 128)] / kdiv[d];
  }
  rr[t] = acc;
  __syncthreads();
  if (t < 128) {
    float s = q1b[t];
    for (int j = 0; j < 256; j++) s = fmaf(rr[j], q1w[j * 128 + t], s);
    h1[t] = fmaxf(s, 0.f);
  }
  __syncthreads();
  if (t < 64) {
    float s = q2b[t];
    for (int j = 0; j < 128; j++) s = fmaf(h1[j], q2w[j * 64 + t], s);
    h2[t] = fmaxf(s, 0.f);
  }
  __syncthreads();
  if (t < 2) {
    float s = q3b[t];
    for (int j = 0; j < 64; j++) s = fmaf(h2[j], q3w[j * 2 + t], s);
    out[b * 2 + t] = s;
  }
}

// ---------- host orchestration ----------
extern "C" void kernel_launch(void* const* d_in, const int* in_sizes, int n_in,
                              void* d_out, int out_size, void* d_ws, size_t ws_size,
                              hipStream_t stream) {
  const float* x = (const float*)d_in[0];
  const int* src = (const int*)d_in[1];
  const int* dst = (const int*)d_in[2];
  const float* q1w = (const float*)d_in[23];
  const float* q1b = (const float*)d_in[24];
  const float* q2w = (const float*)d_in[25];
  const float* q2b = (const float*)d_in[26];
  const float* q3w = (const float*)d_in[27];
  const float* q3b = (const float*)d_in[28];

  char* p = (char*)d_ws;
  auto alloc = [&](size_t bytes) {
    char* q = p;
    p += (bytes + 255) & ~(size_t)255;
    return q;
  };
  float* Xa = (float*)alloc((size_t)NB * N0 * NC * 4);       // pooled x (f32)
  float* Xb = (float*)alloc((size_t)NB * N0 * NC * 4);       // x2 (f32)
  ushort_t* Xh = (ushort_t*)alloc((size_t)NB * N0 * NC * 2); // h0 (bf16)
  int* srcw = (int*)alloc((size_t)NB * NE * 4);
  int* dstw = (int*)alloc((size_t)NB * NE * 4);
  int* elist = (int*)alloc((size_t)NB * NE * 4);
  int* cnt = (int*)alloc((size_t)NB * N0 * 4);
  int* offs = (int*)alloc((size_t)NB * N0 * 4);
  int* cursor = (int*)alloc((size_t)NB * N0 * 4);
  float* score = (float*)alloc((size_t)NB * N0 * 4);
  int* mp = (int*)alloc((size_t)NB * N0 * 4);
  unsigned* vstar = (unsigned*)alloc(256);
  int* quota = (int*)alloc(256);
  int* gcnt = (int*)alloc(NB * 16 * 4);
  int* tcnt = (int*)alloc(NB * 16 * 4);
  int* maxbuf = (int*)alloc(4 * NB * NC * 4);
  float* sumbuf = (float*)alloc(4 * NB * NC * 4);
  ushort_t* Wt_all = (ushort_t*)alloc((size_t)8 * NC * NC * 2);

  hipMemsetAsync(cnt, 0, (size_t)NB * N0 * 4, stream);
  k_init<<<2048, 256, 0, stream>>>(src, dst, srcw, dstw, cnt, maxbuf, sumbuf);
  for (int i = 0; i < 4; i++) {
    k_wprep<<<64, 256, 0, stream>>>((const float*)d_in[3 + i * 5 + 0], Wt_all + (size_t)(2 * i) * NC * NC);
    k_wprep<<<64, 256, 0, stream>>>((const float*)d_in[3 + i * 5 + 2], Wt_all + (size_t)(2 * i + 1) * NC * NC);
  }

  static const int NSv[4] = {16384, 13108, 10487, 8390};
  static const int KSv[4] = {13108, 10487, 8390, 6712};
  for (int i = 0; i < 4; i++) {
    int n = NSv[i], k = KSv[i];
    const float* b1 = (const float*)d_in[3 + i * 5 + 1];
    const float* b2 = (const float*)d_in[3 + i * 5 + 3];
    const float* pw = (const float*)d_in[3 + i * 5 + 4];
    const ushort_t* w1t = Wt_all + (size_t)(2 * i) * NC * NC;
    const ushort_t* w2t = Wt_all + (size_t)(2 * i + 1) * NC * NC;
    const float* cur = (i == 0) ? x : Xa;

    k_scan<<<NB, 1024, 0, stream>>>(cnt, offs, cursor);          // zeroes cnt
    k_fill<<<1024, 256, 0, stream>>>(srcw, dstw, cursor, elist); // cursor -> end offsets

    k_gather<<<((n + 3) / 4) * 8, 256, 0, stream>>>(cur, Xh, offs, cursor, elist, n);

    k_gin<<<((n + 127) / 128) * 8, 256, 0, stream>>>(Xh, Xb, w1t, b1, w2t, b2, pw, score, n);

    k_select<<<NB, 1024, 0, stream>>>(score, vstar, quota, n, k);
    dim3 gm(16, NB);
    k_map_cnt<<<gm, 1024, 0, stream>>>(score, vstar, gcnt, tcnt, n);
    k_map_wr<<<gm, 1024, 0, stream>>>(score, vstar, quota, gcnt, tcnt, mp, n);

    dim3 gs((n + 3) / 4, NB);
    k_compact<<<gs, 256, 0, stream>>>(Xb, Xa, mp, score, n);     // Xa = pooled x
    k_remap<<<1024, 256, 0, stream>>>(srcw, dstw, mp, cnt);      // counts next depth

    dim3 gr(32, NB);
    k_readout<<<gr, 256, 0, stream>>>(Xa, maxbuf + i * NB * NC, sumbuf + i * NB * NC, k);
  }

  k_pred<<<NB, 256, 0, stream>>>(maxbuf, sumbuf, q1w, q1b, q2w, q2b, q3w, q3b, (float*)d_out);
}

// Round 8
// 860.009 us; speedup vs baseline: 4.4301x; 1.1391x over previous
//
#include <hip/hip_runtime.h>
#include <math.h>

#define NB 8
#define N0 16384
#define NC 128
#define NE 98304

typedef unsigned short ushort_t;
using short8 = __attribute__((ext_vector_type(8))) short;
using f32x4 = __attribute__((ext_vector_type(4))) float;

// ---------- helpers ----------
__device__ __forceinline__ unsigned mono_u(float f) {
  unsigned u = __float_as_uint(f);
  return (u & 0x80000000u) ? ~u : (u | 0x80000000u);
}
__device__ __forceinline__ int f2ikey(float f) {
  int i = __float_as_int(f);
  return (i >= 0) ? i : (i ^ 0x7fffffff);
}
__device__ __forceinline__ float ikey2f(int k) {
  return __int_as_float(k >= 0 ? k : (k ^ 0x7fffffff));
}
__device__ __forceinline__ ushort_t f2bf_rne(float f) {
  unsigned u = __float_as_uint(f);
  unsigned r = u + 0x7fffu + ((u >> 16) & 1u);
  return (ushort_t)(r >> 16);
}

// ---------- init: edges copy + depth-0 degree count, readout bufs ----------
// cnt must be pre-zeroed.
__global__ void k_init(const int* __restrict__ src, const int* __restrict__ dst,
                       int* __restrict__ srcw, int* __restrict__ dstw,
                       int* __restrict__ cnt, int* __restrict__ maxbuf, float* __restrict__ sumbuf) {
  int stride = gridDim.x * blockDim.x;
  int i = blockIdx.x * blockDim.x + threadIdx.x;
  for (int j = i; j < NB * NE; j += stride) {
    int d = dst[j];
    srcw[j] = src[j];
    dstw[j] = d;
    atomicAdd(&cnt[(j / NE) * N0 + d], 1);
  }
  for (int j = i; j < 4 * NB * NC; j += stride) {
    maxbuf[j] = (int)0x80000000;
    sumbuf[j] = 0.f;
  }
}

// ---------- weight prep: W[k][c] f32 -> Wt[c][k] bf16 ----------
__global__ void k_wprep(const float* __restrict__ W, ushort_t* __restrict__ Wt) {
  int id = blockIdx.x * blockDim.x + threadIdx.x;
  if (id >= NC * NC) return;
  int k = id >> 7, c = id & 127;
  Wt[c * NC + k] = f2bf_rne(W[id]);
}

// ---------- CSR build: per-graph exclusive scan; zeroes cnt for reuse ----------
__global__ __launch_bounds__(1024) void k_scan(int* __restrict__ cnt,
                                               int* __restrict__ offs, int* __restrict__ cursor) {
  __shared__ int ws[1024];
  int b = blockIdx.x, t = threadIdx.x;
  int base = b * N0 + t * 16;
  int loc[16];
  int s = 0;
#pragma unroll
  for (int j = 0; j < 16; j++) { loc[j] = cnt[base + j]; s += loc[j]; cnt[base + j] = 0; }
  ws[t] = s;
  __syncthreads();
  for (int o = 1; o < 1024; o <<= 1) {
    int v = (t >= o) ? ws[t - o] : 0;
    __syncthreads();
    ws[t] += v;
    __syncthreads();
  }
  int excl = ws[t] - s;
#pragma unroll
  for (int j = 0; j < 16; j++) {
    offs[base + j] = excl;
    cursor[base + j] = excl;
    excl += loc[j];
  }
}

// ---------- CSR build: fill edge list; cursor ends as end-offset ----------
__global__ void k_fill(const int* __restrict__ srcw, const int* __restrict__ dstw,
                       int* __restrict__ cursor, int* __restrict__ elist) {
  int tot = NB * NE;
  for (int i = blockIdx.x * blockDim.x + threadIdx.x; i < tot; i += gridDim.x * blockDim.x) {
    int d = dstw[i];
    if (d < 0) continue;
    int b = i / NE;
    int pos = atomicAdd(&cursor[b * N0 + d], 1);
    elist[b * NE + pos] = srcw[i];
  }
}

// ---------- gather (f32 in, bf16 out): H[node] = bf16( X[node] + sum_{src} X[src] ) ----------
// 1D grid, graph = blockIdx.x & 7 (XCD-pinned). Half-waves, 2 edges per wave-load.
__global__ void k_gather(const float* __restrict__ X, ushort_t* __restrict__ H,
                         const int* __restrict__ offs, const int* __restrict__ cend,
                         const int* __restrict__ elist, int n) {
  int b = blockIdx.x & 7;
  int chunk = blockIdx.x >> 3;
  int lane = threadIdx.x & 63, wid = threadIdx.x >> 6;
  int node = chunk * 4 + wid;
  if (node >= n) return;
  int off = offs[b * N0 + node];
  int deg = cend[b * N0 + node] - off;
  int h = lane >> 5, c4 = lane & 31;
  const float* Xb = X + (size_t)b * N0 * NC;

  float4 acc0 = make_float4(0.f, 0.f, 0.f, 0.f);
  float4 acc1 = make_float4(0.f, 0.f, 0.f, 0.f);
  if (h == 0) acc0 = *reinterpret_cast<const float4*>(&Xb[(size_t)node * NC + c4 * 4]);

  for (int base = 0; base < deg; base += 64) {
    int m = min(64, deg - base);
    int eid = (lane < m) ? elist[b * NE + off + base + lane] : 0;
    int j = 0;
    for (; j + 4 <= m; j += 4) {
      int s0 = __shfl(eid, j + h);
      int s1 = __shfl(eid, j + 2 + h);
      float4 v0 = *reinterpret_cast<const float4*>(&Xb[(size_t)s0 * NC + c4 * 4]);
      float4 v1 = *reinterpret_cast<const float4*>(&Xb[(size_t)s1 * NC + c4 * 4]);
      acc0.x += v0.x; acc0.y += v0.y; acc0.z += v0.z; acc0.w += v0.w;
      acc1.x += v1.x; acc1.y += v1.y; acc1.z += v1.z; acc1.w += v1.w;
    }
    if (j + 2 <= m) {
      int s0 = __shfl(eid, j + h);
      float4 v0 = *reinterpret_cast<const float4*>(&Xb[(size_t)s0 * NC + c4 * 4]);
      acc0.x += v0.x; acc0.y += v0.y; acc0.z += v0.z; acc0.w += v0.w;
      j += 2;
    }
    if (j < m) {
      int s0 = __shfl(eid, j);
      if (h == 0) {
        float4 v0 = *reinterpret_cast<const float4*>(&Xb[(size_t)s0 * NC + c4 * 4]);
        acc0.x += v0.x; acc0.y += v0.y; acc0.z += v0.z; acc0.w += v0.w;
      }
    }
  }
  acc0.x += acc1.x; acc0.y += acc1.y; acc0.z += acc1.z; acc0.w += acc1.w;
  acc0.x += __shfl_xor(acc0.x, 32);
  acc0.y += __shfl_xor(acc0.y, 32);
  acc0.z += __shfl_xor(acc0.z, 32);
  acc0.w += __shfl_xor(acc0.w, 32);
  if (h == 0) {
    unsigned p0 = (unsigned)f2bf_rne(acc0.x) | ((unsigned)f2bf_rne(acc0.y) << 16);
    unsigned p1 = (unsigned)f2bf_rne(acc0.z) | ((unsigned)f2bf_rne(acc0.w) << 16);
    *reinterpret_cast<uint2*>(&H[((size_t)b * N0 + node) * NC + c4 * 4]) = make_uint2(p0, p1);
  }
}

// ---------- fused GIN MLP: x2 = relu(relu(h0@W1+b1)@W2+b2), fused score ----------
// Swapped mfma operands (D: lane=X-row, regs=4 W-cols -> float4 stores); W in LDS.
__global__ __launch_bounds__(256) void k_gin(const ushort_t* __restrict__ Xh,
                                             float* __restrict__ Xout,
                                             const ushort_t* __restrict__ W1t,
                                             const float* __restrict__ b1,
                                             const ushort_t* __restrict__ W2t,
                                             const float* __restrict__ b2,
                                             const float* __restrict__ pw,
                                             float* __restrict__ score, int n) {
  __shared__ ushort_t Ts[128 * 136];
  __shared__ ushort_t Wsh[128 * 136];
  int b = blockIdx.x & 7;
  int r0 = (blockIdx.x >> 3) * 128;
  int t = threadIdx.x;
  const ushort_t* Xg = Xh + (size_t)b * N0 * NC;

#pragma unroll
  for (int p = 0; p < 8; p++) {
    int id = t + p * 256;
    int row = id >> 4, seg = id & 15;
    short8 vh = (short8)0;
    if (r0 + row < n)
      vh = *reinterpret_cast<const short8*>(&Xg[(size_t)(r0 + row) * NC + seg * 8]);
    *reinterpret_cast<short8*>(&Ts[row * 136 + seg * 8]) = vh;
    *reinterpret_cast<short8*>(&Wsh[row * 136 + seg * 8]) =
        *reinterpret_cast<const short8*>(&W1t[row * NC + seg * 8]);
  }
  __syncthreads();

  int lane = t & 63, w = t >> 6;
  int li = lane & 15, lg = lane >> 4;
  int rbase = w * 32;

  f32x4 acc[2][8];
#pragma unroll
  for (int rt = 0; rt < 2; rt++)
#pragma unroll
    for (int ct = 0; ct < 8; ct++) acc[rt][ct] = (f32x4)0.f;

#pragma unroll
  for (int ks = 0; ks < 4; ks++) {
    short8 x0 = *reinterpret_cast<const short8*>(&Ts[(rbase + li) * 136 + ks * 32 + lg * 8]);
    short8 x1 = *reinterpret_cast<const short8*>(&Ts[(rbase + 16 + li) * 136 + ks * 32 + lg * 8]);
#pragma unroll
    for (int ct = 0; ct < 8; ct++) {
      short8 wf = *reinterpret_cast<const short8*>(&Wsh[(ct * 16 + li) * 136 + ks * 32 + lg * 8]);
      acc[0][ct] = __builtin_amdgcn_mfma_f32_16x16x32_bf16(wf, x0, acc[0][ct], 0, 0, 0);
      acc[1][ct] = __builtin_amdgcn_mfma_f32_16x16x32_bf16(wf, x1, acc[1][ct], 0, 0, 0);
    }
  }

#pragma unroll
  for (int rt = 0; rt < 2; rt++) {
    int row = rbase + rt * 16 + li;
#pragma unroll
    for (int ct = 0; ct < 8; ct++) {
      float4 bq = *reinterpret_cast<const float4*>(&b1[ct * 16 + lg * 4]);
      float o0 = fmaxf(acc[rt][ct][0] + bq.x, 0.f);
      float o1 = fmaxf(acc[rt][ct][1] + bq.y, 0.f);
      float o2 = fmaxf(acc[rt][ct][2] + bq.z, 0.f);
      float o3 = fmaxf(acc[rt][ct][3] + bq.w, 0.f);
      unsigned p0 = (unsigned)f2bf_rne(o0) | ((unsigned)f2bf_rne(o1) << 16);
      unsigned p1 = (unsigned)f2bf_rne(o2) | ((unsigned)f2bf_rne(o3) << 16);
      *reinterpret_cast<uint2*>(&Ts[row * 136 + ct * 16 + lg * 4]) = make_uint2(p0, p1);
    }
  }

  __syncthreads();
#pragma unroll
  for (int p = 0; p < 8; p++) {
    int id = t + p * 256;
    int row = id >> 4, seg = id & 15;
    *reinterpret_cast<short8*>(&Wsh[row * 136 + seg * 8]) =
        *reinterpret_cast<const short8*>(&W2t[row * NC + seg * 8]);
  }
  __syncthreads();

#pragma unroll
  for (int rt = 0; rt < 2; rt++)
#pragma unroll
    for (int ct = 0; ct < 8; ct++) acc[rt][ct] = (f32x4)0.f;

#pragma unroll
  for (int ks = 0; ks < 4; ks++) {
    short8 x0 = *reinterpret_cast<const short8*>(&Ts[(rbase + li) * 136 + ks * 32 + lg * 8]);
    short8 x1 = *reinterpret_cast<const short8*>(&Ts[(rbase + 16 + li) * 136 + ks * 32 + lg * 8]);
#pragma unroll
    for (int ct = 0; ct < 8; ct++) {
      short8 wf = *reinterpret_cast<const short8*>(&Wsh[(ct * 16 + li) * 136 + ks * 32 + lg * 8]);
      acc[0][ct] = __builtin_amdgcn_mfma_f32_16x16x32_bf16(wf, x0, acc[0][ct], 0, 0, 0);
      acc[1][ct] = __builtin_amdgcn_mfma_f32_16x16x32_bf16(wf, x1, acc[1][ct], 0, 0, 0);
    }
  }

  f32x4 pq[8];
  float psum = 0.f;
#pragma unroll
  for (int ct = 0; ct < 8; ct++) {
    pq[ct] = *reinterpret_cast<const f32x4*>(&pw[ct * 16 + lg * 4]);
    psum = fmaf(pq[ct][0], pq[ct][0], psum);
    psum = fmaf(pq[ct][1], pq[ct][1], psum);
    psum = fmaf(pq[ct][2], pq[ct][2], psum);
    psum = fmaf(pq[ct][3], pq[ct][3], psum);
  }
  psum += __shfl_xor(psum, 16);
  psum += __shfl_xor(psum, 32);
  float nrm = sqrtf(psum);

  float* Ob = Xout + (size_t)b * N0 * NC;
#pragma unroll
  for (int rt = 0; rt < 2; rt++) {
    int row = r0 + rbase + rt * 16 + li;
    bool ok = row < n;
    float dot = 0.f;
#pragma unroll
    for (int ct = 0; ct < 8; ct++) {
      float4 bq = *reinterpret_cast<const float4*>(&b2[ct * 16 + lg * 4]);
      float4 o;
      o.x = fmaxf(acc[rt][ct][0] + bq.x, 0.f);
      o.y = fmaxf(acc[rt][ct][1] + bq.y, 0.f);
      o.z = fmaxf(acc[rt][ct][2] + bq.z, 0.f);
      o.w = fmaxf(acc[rt][ct][3] + bq.w, 0.f);
      dot = fmaf(o.x, pq[ct][0], dot);
      dot = fmaf(o.y, pq[ct][1], dot);
      dot = fmaf(o.z, pq[ct][2], dot);
      dot = fmaf(o.w, pq[ct][3], dot);
      if (ok) *reinterpret_cast<float4*>(&Ob[(size_t)row * NC + ct * 16 + lg * 4]) = o;
    }
    dot += __shfl_xor(dot, 16);
    dot += __shfl_xor(dot, 32);
    if (lg == 0 && ok) score[b * N0 + row] = tanhf(dot / nrm);
  }
}

// ---------- top-k threshold via 4-pass radix select + fused per-chunk counts ----------
__global__ __launch_bounds__(1024) void k_select(const float* __restrict__ score,
                                                 unsigned* __restrict__ vstar, int* __restrict__ quota,
                                                 int* __restrict__ gcnt, int* __restrict__ tcnt,
                                                 int n, int k) {
  __shared__ int hist[256];
  __shared__ unsigned s_pref;
  __shared__ int s_r, s_gt;
  int b = blockIdx.x, t = threadIdx.x, lane = t & 63;
  if (t == 0) { s_pref = 0u; s_r = k; s_gt = 0; }
  __syncthreads();
  for (int pass = 0; pass < 4; ++pass) {
    int shift = 24 - pass * 8;
    if (t < 256) hist[t] = 0;
    __syncthreads();
    unsigned pref = s_pref;
    unsigned pmask = (pass == 0) ? 0u : (0xFFFFFFFFu << (shift + 8));
    for (int j0 = 0; j0 < n; j0 += 1024) {
      int j = j0 + t;
      unsigned key = (j < n) ? mono_u(score[b * N0 + j]) : 0u;
      unsigned d = (key >> shift) & 255;
      int contrib = (j < n) && ((key & pmask) == pref);
      unsigned long long bal = __ballot(contrib);
      if (bal == 0) continue;
      int fl = __ffsll((long long)bal) - 1;
      unsigned dref = __shfl(d, fl);
      if (__all(!contrib || d == dref)) {
        if (lane == fl) atomicAdd(&hist[dref], (int)__popcll(bal));
      } else if (contrib) {
        atomicAdd(&hist[d], 1);
      }
    }
    __syncthreads();
    if (t == 0) {
      int r = s_r, acc = 0, d = 255;
      for (; d >= 0; --d) {
        if (acc + hist[d] >= r) break;
        acc += hist[d];
      }
      s_gt += acc;
      s_r = r - acc;
      s_pref = pref | ((unsigned)d << shift);
    }
    __syncthreads();
  }
  if (t == 0) {
    vstar[b] = s_pref;
    quota[b] = k - s_gt;
  }
  __syncthreads();
  // fused per-chunk gt/tie counts (wave w owns chunk w)
  unsigned vs = s_pref;
  int w = t >> 6;
  int g = 0, tt = 0;
  for (int it = 0; it < 16; ++it) {
    int j = w * 1024 + it * 64 + lane;
    unsigned key = (j < n) ? mono_u(score[b * N0 + j]) : 0u;
    g += (int)__popcll(__ballot((j < n) && (key > vs)));
    tt += (int)__popcll(__ballot((j < n) && (key == vs)));
  }
  if (lane == 0) { gcnt[b * 16 + w] = g; tcnt[b * 16 + w] = tt; }
}

// ---------- map: assign new ids, jax.lax.top_k tie semantics ----------
__global__ __launch_bounds__(1024) void k_map_wr(const float* __restrict__ score,
                                                 const unsigned* __restrict__ vstar,
                                                 const int* __restrict__ quota,
                                                 const int* __restrict__ gcnt, const int* __restrict__ tcnt,
                                                 int* __restrict__ mp, int n) {
  __shared__ int wg[16], wt[16];
  __shared__ int s_gb, s_tb;
  int b = blockIdx.y, chunk = blockIdx.x, t = threadIdx.x;
  int lane = t & 63, wid = t >> 6;
  if (t == 0) {
    int gb = 0, tb = 0;
    for (int c = 0; c < chunk; c++) { gb += gcnt[b * 16 + c]; tb += tcnt[b * 16 + c]; }
    s_gb = gb; s_tb = tb;
  }
  int j = chunk * 1024 + t;
  unsigned vs = vstar[b];
  int q = quota[b];
  unsigned key = (j < n) ? mono_u(score[b * N0 + j]) : 0u;
  int gt = (j < n) && (key > vs);
  int tie = (j < n) && (key == vs);
  unsigned long long bg = __ballot(gt), bt = __ballot(tie);
  if (lane == 0) { wg[wid] = (int)__popcll(bg); wt[wid] = (int)__popcll(bt); }
  __syncthreads();
  if (j >= n) return;
  unsigned long long ltm = (lane == 63) ? ~0ull >> 1 : ((1ull << lane) - 1);
  int gloc = (int)__popcll(bg & ltm);
  int tloc = (int)__popcll(bt & ltm);
  for (int w = 0; w < 16; w++) {
    if (w < wid) { gloc += wg[w]; tloc += wt[w]; }
  }
  int tie_rank = s_tb + tloc;
  int sel = gt || (tie && tie_rank < q);
  int pos = s_gb + gloc + min(tie_rank, q);
  mp[b * N0 + j] = sel ? pos : -1;
}

// ---------- compact (fused readout, XCD-pinned): Xa[m] = x2[node]*val (f32) ----------
__global__ __launch_bounds__(256) void k_compact(const float* __restrict__ Xin,
                                                 float* __restrict__ Xout,
                                                 const int* __restrict__ mp,
                                                 const float* __restrict__ score,
                                                 int* __restrict__ maxbuf, float* __restrict__ sumbuf,
                                                 int n) {
  __shared__ float smx[128], ssm[128];
  int b = blockIdx.x & 7;
  int base = (blockIdx.x >> 3) * 64;
  if (base >= n) return;
  int c = threadIdx.x & 127, h = threadIdx.x >> 7;
  float mx = -INFINITY, sm = 0.f;
  for (int r = h; r < 64; r += 2) {
    int node = base + r;
    if (node >= n) break;
    int m = mp[b * N0 + node];
    if (m < 0) continue;
    float val = score[b * N0 + node];
    float v = Xin[((size_t)b * N0 + node) * NC + c] * val;
    Xout[((size_t)b * N0 + m) * NC + c] = v;
    mx = fmaxf(mx, v);
    sm += v;
  }
  if (h) { smx[c] = mx; ssm[c] = sm; }
  __syncthreads();
  if (!h) {
    mx = fmaxf(mx, smx[c]);
    sm += ssm[c];
    atomicMax(&maxbuf[b * NC + c], f2ikey(mx));
    atomicAdd(&sumbuf[b * NC + c], sm);
  }
}

// ---------- remap edges in place; count next-depth in-degrees ----------
__global__ void k_remap(int* __restrict__ srcw, int* __restrict__ dstw,
                        const int* __restrict__ mp, int* __restrict__ cnt) {
  int tot = NB * NE;
  int tid = blockIdx.x * blockDim.x + threadIdx.x;
  int stride = gridDim.x * blockDim.x;
  for (int i = tid; i < tot; i += stride) {
    int d = dstw[i];
    if (d < 0) continue;
    int b = i / NE;
    int s = srcw[i];
    int ns = mp[b * N0 + s], nd = mp[b * N0 + d];
    if (ns >= 0 && nd >= 0) {
      srcw[i] = ns;
      dstw[i] = nd;
      atomicAdd(&cnt[b * N0 + nd], 1);
    } else {
      srcw[i] = 0;
      dstw[i] = -1;
    }
  }
}

// ---------- predictor MLP (folds readout-sum across depths) ----------
__global__ __launch_bounds__(256) void k_pred(const int* __restrict__ maxbuf,
                                              const float* __restrict__ sumbuf,
                                              const float* __restrict__ q1w, const float* __restrict__ q1b,
                                              const float* __restrict__ q2w, const float* __restrict__ q2b,
                                              const float* __restrict__ q3w, const float* __restrict__ q3b,
                                              float* __restrict__ out) {
  __shared__ float rr[256], h1[128], h2[64];
  int b = blockIdx.x, t = threadIdx.x;
  const float kdiv[4] = {13108.f, 10487.f, 8390.f, 6712.f};
  float acc = 0.f;
#pragma unroll
  for (int d = 0; d < 4; d++) {
    if (t < 128) acc += ikey2f(maxbuf[d * NB * NC + b * NC + t]);
    else acc += sumbuf[d * NB * NC + b * NC + (t - 128)] / kdiv[d];
  }
  rr[t] = acc;
  __syncthreads();
  if (t < 128) {
    float s = q1b[t];
    for (int j = 0; j < 256; j++) s = fmaf(rr[j], q1w[j * 128 + t], s);
    h1[t] = fmaxf(s, 0.f);
  }
  __syncthreads();
  if (t < 64) {
    float s = q2b[t];
    for (int j = 0; j < 128; j++) s = fmaf(h1[j], q2w[j * 64 + t], s);
    h2[t] = fmaxf(s, 0.f);
  }
  __syncthreads();
  if (t < 2) {
    float s = q3b[t];
    for (int j = 0; j < 64; j++) s = fmaf(h2[j], q3w[j * 2 + t], s);
    out[b * 2 + t] = s;
  }
}

// ---------- host orchestration ----------
extern "C" void kernel_launch(void* const* d_in, const int* in_sizes, int n_in,
                              void* d_out, int out_size, void* d_ws, size_t ws_size,
                              hipStream_t stream) {
  const float* x = (const float*)d_in[0];
  const int* src = (const int*)d_in[1];
  const int* dst = (const int*)d_in[2];
  const float* q1w = (const float*)d_in[23];
  const float* q1b = (const float*)d_in[24];
  const float* q2w = (const float*)d_in[25];
  const float* q2b = (const float*)d_in[26];
  const float* q3w = (const float*)d_in[27];
  const float* q3b = (const float*)d_in[28];

  char* p = (char*)d_ws;
  auto alloc = [&](size_t bytes) {
    char* q = p;
    p += (bytes + 255) & ~(size_t)255;
    return q;
  };
  float* Xa = (float*)alloc((size_t)NB * N0 * NC * 4);       // pooled x (f32)
  float* Xb = (float*)alloc((size_t)NB * N0 * NC * 4);       // x2 (f32, gin out)
  ushort_t* Xh = (ushort_t*)alloc((size_t)NB * N0 * NC * 2); // h0 (bf16)
  int* srcw = (int*)alloc((size_t)NB * NE * 4);
  int* dstw = (int*)alloc((size_t)NB * NE * 4);
  int* elist = (int*)alloc((size_t)NB * NE * 4);
  int* cnt = (int*)alloc((size_t)NB * N0 * 4);
  int* offs = (int*)alloc((size_t)NB * N0 * 4);
  int* cursor = (int*)alloc((size_t)NB * N0 * 4);
  float* score = (float*)alloc((size_t)NB * N0 * 4);
  int* mp = (int*)alloc((size_t)NB * N0 * 4);
  unsigned* vstar = (unsigned*)alloc(256);
  int* quota = (int*)alloc(256);
  int* gcnt = (int*)alloc(NB * 16 * 4);
  int* tcnt = (int*)alloc(NB * 16 * 4);
  int* maxbuf = (int*)alloc(4 * NB * NC * 4);
  float* sumbuf = (float*)alloc(4 * NB * NC * 4);
  ushort_t* Wt_all = (ushort_t*)alloc((size_t)8 * NC * NC * 2);

  hipMemsetAsync(cnt, 0, (size_t)NB * N0 * 4, stream);
  k_init<<<2048, 256, 0, stream>>>(src, dst, srcw, dstw, cnt, maxbuf, sumbuf);
  for (int i = 0; i < 4; i++) {
    k_wprep<<<64, 256, 0, stream>>>((const float*)d_in[3 + i * 5 + 0], Wt_all + (size_t)(2 * i) * NC * NC);
    k_wprep<<<64, 256, 0, stream>>>((const float*)d_in[3 + i * 5 + 2], Wt_all + (size_t)(2 * i + 1) * NC * NC);
  }

  static const int NSv[4] = {16384, 13108, 10487, 8390};
  static const int KSv[4] = {13108, 10487, 8390, 6712};
  for (int i = 0; i < 4; i++) {
    int n = NSv[i], k = KSv[i];
    const float* b1 = (const float*)d_in[3 + i * 5 + 1];
    const float* b2 = (const float*)d_in[3 + i * 5 + 3];
    const float* pw = (const float*)d_in[3 + i * 5 + 4];
    const ushort_t* w1t = Wt_all + (size_t)(2 * i) * NC * NC;
    const ushort_t* w2t = Wt_all + (size_t)(2 * i + 1) * NC * NC;
    const float* cur = (i == 0) ? x : Xa;

    k_scan<<<NB, 1024, 0, stream>>>(cnt, offs, cursor);
    k_fill<<<1024, 256, 0, stream>>>(srcw, dstw, cursor, elist);

    k_gather<<<((n + 3) / 4) * 8, 256, 0, stream>>>(cur, Xh, offs, cursor, elist, n);

    k_gin<<<((n + 127) / 128) * 8, 256, 0, stream>>>(Xh, Xb, w1t, b1, w2t, b2, pw, score, n);

    k_select<<<NB, 1024, 0, stream>>>(score, vstar, quota, gcnt, tcnt, n, k);
    dim3 gm(16, NB);
    k_map_wr<<<gm, 1024, 0, stream>>>(score, vstar, quota, gcnt, tcnt, mp, n);

    k_compact<<<((n + 63) / 64) * 8, 256, 0, stream>>>(Xb, Xa, mp, score,
                                                       maxbuf + i * NB * NC, sumbuf + i * NB * NC, n);
    k_remap<<<1024, 256, 0, stream>>>(srcw, dstw, mp, cnt);
  }

  k_pred<<<NB, 256, 0, stream>>>(maxbuf, sumbuf, q1w, q1b, q2w, q2b, q3w, q3b, (float*)d_out);
}

// Round 9
// 734.270 us; speedup vs baseline: 5.1888x; 1.1712x over previous
//
#include <hip/hip_runtime.h>
#include <math.h>

#define NB 8
#define N0 16384
#define NC 128
#define NE 98304

typedef unsigned short ushort_t;
using short8 = __attribute__((ext_vector_type(8))) short;
using f32x4 = __attribute__((ext_vector_type(4))) float;

// ---------- helpers ----------
__device__ __forceinline__ unsigned mono_u(float f) {
  unsigned u = __float_as_uint(f);
  return (u & 0x80000000u) ? ~u : (u | 0x80000000u);
}
__device__ __forceinline__ int f2ikey(float f) {
  int i = __float_as_int(f);
  return (i >= 0) ? i : (i ^ 0x7fffffff);
}
__device__ __forceinline__ float ikey2f(int k) {
  return __int_as_float(k >= 0 ? k : (k ^ 0x7fffffff));
}
__device__ __forceinline__ ushort_t f2bf_rne(float f) {
  unsigned u = __float_as_uint(f);
  unsigned r = u + 0x7fffu + ((u >> 16) & 1u);
  return (ushort_t)(r >> 16);
}

// ---------- init: edges copy + depth-0 degree count, readout bufs ----------
// cnt must be pre-zeroed.
__global__ void k_init(const int* __restrict__ src, const int* __restrict__ dst,
                       int* __restrict__ srcw, int* __restrict__ dstw,
                       int* __restrict__ cnt, int* __restrict__ maxbuf, float* __restrict__ sumbuf) {
  int stride = gridDim.x * blockDim.x;
  int i = blockIdx.x * blockDim.x + threadIdx.x;
  for (int j = i; j < NB * NE; j += stride) {
    int d = dst[j];
    srcw[j] = src[j];
    dstw[j] = d;
    atomicAdd(&cnt[(j / NE) * N0 + d], 1);
  }
  for (int j = i; j < 4 * NB * NC; j += stride) {
    maxbuf[j] = (int)0x80000000;
    sumbuf[j] = 0.f;
  }
}

// ---------- weight prep: W[k][c] f32 -> Wt[c][k] bf16 ----------
__global__ void k_wprep(const float* __restrict__ W, ushort_t* __restrict__ Wt) {
  int id = blockIdx.x * blockDim.x + threadIdx.x;
  if (id >= NC * NC) return;
  int k = id >> 7, c = id & 127;
  Wt[c * NC + k] = f2bf_rne(W[id]);
}

// ---------- CSR build: per-graph exclusive scan; zeroes cnt for reuse ----------
__global__ __launch_bounds__(1024) void k_scan(int* __restrict__ cnt,
                                               int* __restrict__ offs, int* __restrict__ cursor) {
  __shared__ int ws[1024];
  int b = blockIdx.x, t = threadIdx.x;
  int base = b * N0 + t * 16;
  int loc[16];
  int s = 0;
#pragma unroll
  for (int j = 0; j < 16; j++) { loc[j] = cnt[base + j]; s += loc[j]; cnt[base + j] = 0; }
  ws[t] = s;
  __syncthreads();
  for (int o = 1; o < 1024; o <<= 1) {
    int v = (t >= o) ? ws[t - o] : 0;
    __syncthreads();
    ws[t] += v;
    __syncthreads();
  }
  int excl = ws[t] - s;
#pragma unroll
  for (int j = 0; j < 16; j++) {
    offs[base + j] = excl;
    cursor[base + j] = excl;
    excl += loc[j];
  }
}

// ---------- CSR build: fill edge list; cursor ends as end-offset ----------
__global__ void k_fill(const int* __restrict__ srcw, const int* __restrict__ dstw,
                       int* __restrict__ cursor, int* __restrict__ elist) {
  int tot = NB * NE;
  for (int i = blockIdx.x * blockDim.x + threadIdx.x; i < tot; i += gridDim.x * blockDim.x) {
    int d = dstw[i];
    if (d < 0) continue;
    int b = i / NE;
    int pos = atomicAdd(&cursor[b * N0 + d], 1);
    elist[b * NE + pos] = srcw[i];
  }
}

// ---------- gather (f32 in, bf16 out): H[node] = bf16( X[node] + sum_{src} X[src] ) ----------
// 1D grid, graph = blockIdx.x & 7 (XCD-pinned). Half-waves, 2 edges per wave-load.
__global__ void k_gather(const float* __restrict__ X, ushort_t* __restrict__ H,
                         const int* __restrict__ offs, const int* __restrict__ cend,
                         const int* __restrict__ elist, int n) {
  int b = blockIdx.x & 7;
  int chunk = blockIdx.x >> 3;
  int lane = threadIdx.x & 63, wid = threadIdx.x >> 6;
  int node = chunk * 4 + wid;
  if (node >= n) return;
  int off = offs[b * N0 + node];
  int deg = cend[b * N0 + node] - off;
  int h = lane >> 5, c4 = lane & 31;
  const float* Xb = X + (size_t)b * N0 * NC;

  float4 acc0 = make_float4(0.f, 0.f, 0.f, 0.f);
  float4 acc1 = make_float4(0.f, 0.f, 0.f, 0.f);
  if (h == 0) acc0 = *reinterpret_cast<const float4*>(&Xb[(size_t)node * NC + c4 * 4]);

  for (int base = 0; base < deg; base += 64) {
    int m = min(64, deg - base);
    int eid = (lane < m) ? elist[b * NE + off + base + lane] : 0;
    int j = 0;
    for (; j + 4 <= m; j += 4) {
      int s0 = __shfl(eid, j + h);
      int s1 = __shfl(eid, j + 2 + h);
      float4 v0 = *reinterpret_cast<const float4*>(&Xb[(size_t)s0 * NC + c4 * 4]);
      float4 v1 = *reinterpret_cast<const float4*>(&Xb[(size_t)s1 * NC + c4 * 4]);
      acc0.x += v0.x; acc0.y += v0.y; acc0.z += v0.z; acc0.w += v0.w;
      acc1.x += v1.x; acc1.y += v1.y; acc1.z += v1.z; acc1.w += v1.w;
    }
    if (j + 2 <= m) {
      int s0 = __shfl(eid, j + h);
      float4 v0 = *reinterpret_cast<const float4*>(&Xb[(size_t)s0 * NC + c4 * 4]);
      acc0.x += v0.x; acc0.y += v0.y; acc0.z += v0.z; acc0.w += v0.w;
      j += 2;
    }
    if (j < m) {
      int s0 = __shfl(eid, j);
      if (h == 0) {
        float4 v0 = *reinterpret_cast<const float4*>(&Xb[(size_t)s0 * NC + c4 * 4]);
        acc0.x += v0.x; acc0.y += v0.y; acc0.z += v0.z; acc0.w += v0.w;
      }
    }
  }
  acc0.x += acc1.x; acc0.y += acc1.y; acc0.z += acc1.z; acc0.w += acc1.w;
  acc0.x += __shfl_xor(acc0.x, 32);
  acc0.y += __shfl_xor(acc0.y, 32);
  acc0.z += __shfl_xor(acc0.z, 32);
  acc0.w += __shfl_xor(acc0.w, 32);
  if (h == 0) {
    unsigned p0 = (unsigned)f2bf_rne(acc0.x) | ((unsigned)f2bf_rne(acc0.y) << 16);
    unsigned p1 = (unsigned)f2bf_rne(acc0.z) | ((unsigned)f2bf_rne(acc0.w) << 16);
    *reinterpret_cast<uint2*>(&H[((size_t)b * N0 + node) * NC + c4 * 4]) = make_uint2(p0, p1);
  }
}

// ---------- fused GIN MLP: x2 = relu(relu(h0@W1+b1)@W2+b2), fused score ----------
// Swapped mfma operands (D: lane=X-row, regs=4 W-cols -> float4 stores); W in LDS.
__global__ __launch_bounds__(256) void k_gin(const ushort_t* __restrict__ Xh,
                                             float* __restrict__ Xout,
                                             const ushort_t* __restrict__ W1t,
                                             const float* __restrict__ b1,
                                             const ushort_t* __restrict__ W2t,
                                             const float* __restrict__ b2,
                                             const float* __restrict__ pw,
                                             float* __restrict__ score, int n) {
  __shared__ ushort_t Ts[128 * 136];
  __shared__ ushort_t Wsh[128 * 136];
  int b = blockIdx.x & 7;
  int r0 = (blockIdx.x >> 3) * 128;
  int t = threadIdx.x;
  const ushort_t* Xg = Xh + (size_t)b * N0 * NC;

#pragma unroll
  for (int p = 0; p < 8; p++) {
    int id = t + p * 256;
    int row = id >> 4, seg = id & 15;
    short8 vh = (short8)0;
    if (r0 + row < n)
      vh = *reinterpret_cast<const short8*>(&Xg[(size_t)(r0 + row) * NC + seg * 8]);
    *reinterpret_cast<short8*>(&Ts[row * 136 + seg * 8]) = vh;
    *reinterpret_cast<short8*>(&Wsh[row * 136 + seg * 8]) =
        *reinterpret_cast<const short8*>(&W1t[row * NC + seg * 8]);
  }
  __syncthreads();

  int lane = t & 63, w = t >> 6;
  int li = lane & 15, lg = lane >> 4;
  int rbase = w * 32;

  f32x4 acc[2][8];
#pragma unroll
  for (int rt = 0; rt < 2; rt++)
#pragma unroll
    for (int ct = 0; ct < 8; ct++) acc[rt][ct] = (f32x4)0.f;

#pragma unroll
  for (int ks = 0; ks < 4; ks++) {
    short8 x0 = *reinterpret_cast<const short8*>(&Ts[(rbase + li) * 136 + ks * 32 + lg * 8]);
    short8 x1 = *reinterpret_cast<const short8*>(&Ts[(rbase + 16 + li) * 136 + ks * 32 + lg * 8]);
#pragma unroll
    for (int ct = 0; ct < 8; ct++) {
      short8 wf = *reinterpret_cast<const short8*>(&Wsh[(ct * 16 + li) * 136 + ks * 32 + lg * 8]);
      acc[0][ct] = __builtin_amdgcn_mfma_f32_16x16x32_bf16(wf, x0, acc[0][ct], 0, 0, 0);
      acc[1][ct] = __builtin_amdgcn_mfma_f32_16x16x32_bf16(wf, x1, acc[1][ct], 0, 0, 0);
    }
  }

#pragma unroll
  for (int rt = 0; rt < 2; rt++) {
    int row = rbase + rt * 16 + li;
#pragma unroll
    for (int ct = 0; ct < 8; ct++) {
      float4 bq = *reinterpret_cast<const float4*>(&b1[ct * 16 + lg * 4]);
      float o0 = fmaxf(acc[rt][ct][0] + bq.x, 0.f);
      float o1 = fmaxf(acc[rt][ct][1] + bq.y, 0.f);
      float o2 = fmaxf(acc[rt][ct][2] + bq.z, 0.f);
      float o3 = fmaxf(acc[rt][ct][3] + bq.w, 0.f);
      unsigned p0 = (unsigned)f2bf_rne(o0) | ((unsigned)f2bf_rne(o1) << 16);
      unsigned p1 = (unsigned)f2bf_rne(o2) | ((unsigned)f2bf_rne(o3) << 16);
      *reinterpret_cast<uint2*>(&Ts[row * 136 + ct * 16 + lg * 4]) = make_uint2(p0, p1);
    }
  }

  __syncthreads();
#pragma unroll
  for (int p = 0; p < 8; p++) {
    int id = t + p * 256;
    int row = id >> 4, seg = id & 15;
    *reinterpret_cast<short8*>(&Wsh[row * 136 + seg * 8]) =
        *reinterpret_cast<const short8*>(&W2t[row * NC + seg * 8]);
  }
  __syncthreads();

#pragma unroll
  for (int rt = 0; rt < 2; rt++)
#pragma unroll
    for (int ct = 0; ct < 8; ct++) acc[rt][ct] = (f32x4)0.f;

#pragma unroll
  for (int ks = 0; ks < 4; ks++) {
    short8 x0 = *reinterpret_cast<const short8*>(&Ts[(rbase + li) * 136 + ks * 32 + lg * 8]);
    short8 x1 = *reinterpret_cast<const short8*>(&Ts[(rbase + 16 + li) * 136 + ks * 32 + lg * 8]);
#pragma unroll
    for (int ct = 0; ct < 8; ct++) {
      short8 wf = *reinterpret_cast<const short8*>(&Wsh[(ct * 16 + li) * 136 + ks * 32 + lg * 8]);
      acc[0][ct] = __builtin_amdgcn_mfma_f32_16x16x32_bf16(wf, x0, acc[0][ct], 0, 0, 0);
      acc[1][ct] = __builtin_amdgcn_mfma_f32_16x16x32_bf16(wf, x1, acc[1][ct], 0, 0, 0);
    }
  }

  f32x4 pq[8];
  float psum = 0.f;
#pragma unroll
  for (int ct = 0; ct < 8; ct++) {
    pq[ct] = *reinterpret_cast<const f32x4*>(&pw[ct * 16 + lg * 4]);
    psum = fmaf(pq[ct][0], pq[ct][0], psum);
    psum = fmaf(pq[ct][1], pq[ct][1], psum);
    psum = fmaf(pq[ct][2], pq[ct][2], psum);
    psum = fmaf(pq[ct][3], pq[ct][3], psum);
  }
  psum += __shfl_xor(psum, 16);
  psum += __shfl_xor(psum, 32);
  float nrm = sqrtf(psum);

  float* Ob = Xout + (size_t)b * N0 * NC;
#pragma unroll
  for (int rt = 0; rt < 2; rt++) {
    int row = r0 + rbase + rt * 16 + li;
    bool ok = row < n;
    float dot = 0.f;
#pragma unroll
    for (int ct = 0; ct < 8; ct++) {
      float4 bq = *reinterpret_cast<const float4*>(&b2[ct * 16 + lg * 4]);
      float4 o;
      o.x = fmaxf(acc[rt][ct][0] + bq.x, 0.f);
      o.y = fmaxf(acc[rt][ct][1] + bq.y, 0.f);
      o.z = fmaxf(acc[rt][ct][2] + bq.z, 0.f);
      o.w = fmaxf(acc[rt][ct][3] + bq.w, 0.f);
      dot = fmaf(o.x, pq[ct][0], dot);
      dot = fmaf(o.y, pq[ct][1], dot);
      dot = fmaf(o.z, pq[ct][2], dot);
      dot = fmaf(o.w, pq[ct][3], dot);
      if (ok) *reinterpret_cast<float4*>(&Ob[(size_t)row * NC + ct * 16 + lg * 4]) = o;
    }
    dot += __shfl_xor(dot, 16);
    dot += __shfl_xor(dot, 32);
    if (lg == 0 && ok) score[b * N0 + row] = tanhf(dot / nrm);
  }
}

// ---------- top-k threshold via 4-pass radix select (parallel digit scan) ----------
__global__ __launch_bounds__(1024) void k_select(const float* __restrict__ score,
                                                 unsigned* __restrict__ vstar, int* __restrict__ quota,
                                                 int* __restrict__ gcnt, int* __restrict__ tcnt,
                                                 int n, int k) {
  __shared__ int hist[256];
  __shared__ int ss[257];
  __shared__ unsigned s_pref;
  __shared__ int s_r, s_gt;
  int b = blockIdx.x, t = threadIdx.x, lane = t & 63;
  if (t == 0) { s_pref = 0u; s_r = k; s_gt = 0; }
  __syncthreads();
  for (int pass = 0; pass < 4; ++pass) {
    int shift = 24 - pass * 8;
    if (t < 256) hist[t] = 0;
    __syncthreads();
    unsigned pref = s_pref;
    unsigned pmask = (pass == 0) ? 0u : (0xFFFFFFFFu << (shift + 8));
    for (int j0 = 0; j0 < n; j0 += 1024) {
      int j = j0 + t;
      unsigned key = (j < n) ? mono_u(score[b * N0 + j]) : 0u;
      unsigned d = (key >> shift) & 255;
      int contrib = (j < n) && ((key & pmask) == pref);
      unsigned long long bal = __ballot(contrib);
      if (bal == 0) continue;
      int fl = __ffsll((long long)bal) - 1;
      unsigned dref = __shfl(d, fl);
      if (__all(!contrib || d == dref)) {
        if (lane == fl) atomicAdd(&hist[dref], (int)__popcll(bal));
      } else if (contrib) {
        atomicAdd(&hist[d], 1);
      }
    }
    __syncthreads();
    // parallel suffix-sum over 256 bins (Hillis-Steele, 8 steps)
    if (t < 256) ss[t] = hist[t];
    __syncthreads();
    for (int o = 1; o < 256; o <<= 1) {
      int v = 0;
      if (t < 256) v = (t + o < 256) ? ss[t + o] : 0;
      __syncthreads();
      if (t < 256) ss[t] += v;
      __syncthreads();
    }
    int r = s_r;
    __syncthreads();
    if (t < 256) {
      int nxt = (t == 255) ? 0 : ss[t + 1];
      if (ss[t] >= r && nxt < r) {   // unique digit: largest d with suffix >= r
        s_gt += nxt;
        s_r = r - nxt;
        s_pref = pref | ((unsigned)t << shift);
      }
    }
    __syncthreads();
  }
  if (t == 0) {
    vstar[b] = s_pref;
    quota[b] = k - s_gt;
  }
  __syncthreads();
  // fused per-chunk gt/tie counts (wave w owns chunk w)
  unsigned vs = s_pref;
  int w = t >> 6;
  int g = 0, tt = 0;
  for (int it = 0; it < 16; ++it) {
    int j = w * 1024 + it * 64 + lane;
    unsigned key = (j < n) ? mono_u(score[b * N0 + j]) : 0u;
    g += (int)__popcll(__ballot((j < n) && (key > vs)));
    tt += (int)__popcll(__ballot((j < n) && (key == vs)));
  }
  if (lane == 0) { gcnt[b * 16 + w] = g; tcnt[b * 16 + w] = tt; }
}

// ---------- map: assign new ids, jax.lax.top_k tie semantics ----------
__global__ __launch_bounds__(1024) void k_map_wr(const float* __restrict__ score,
                                                 const unsigned* __restrict__ vstar,
                                                 const int* __restrict__ quota,
                                                 const int* __restrict__ gcnt, const int* __restrict__ tcnt,
                                                 int* __restrict__ mp, int n) {
  __shared__ int wg[16], wt[16];
  __shared__ int s_gb, s_tb;
  int b = blockIdx.y, chunk = blockIdx.x, t = threadIdx.x;
  int lane = t & 63, wid = t >> 6;
  if (t == 0) {
    int gb = 0, tb = 0;
    for (int c = 0; c < chunk; c++) { gb += gcnt[b * 16 + c]; tb += tcnt[b * 16 + c]; }
    s_gb = gb; s_tb = tb;
  }
  int j = chunk * 1024 + t;
  unsigned vs = vstar[b];
  int q = quota[b];
  unsigned key = (j < n) ? mono_u(score[b * N0 + j]) : 0u;
  int gt = (j < n) && (key > vs);
  int tie = (j < n) && (key == vs);
  unsigned long long bg = __ballot(gt), bt = __ballot(tie);
  if (lane == 0) { wg[wid] = (int)__popcll(bg); wt[wid] = (int)__popcll(bt); }
  __syncthreads();
  if (j >= n) return;
  unsigned long long ltm = (lane == 63) ? ~0ull >> 1 : ((1ull << lane) - 1);
  int gloc = (int)__popcll(bg & ltm);
  int tloc = (int)__popcll(bt & ltm);
  for (int w = 0; w < 16; w++) {
    if (w < wid) { gloc += wg[w]; tloc += wt[w]; }
  }
  int tie_rank = s_tb + tloc;
  int sel = gt || (tie && tie_rank < q);
  int pos = s_gb + gloc + min(tie_rank, q);
  mp[b * N0 + j] = sel ? pos : -1;
}

// ---------- compact (fused readout, XCD-pinned): Xa[m] = x2[node]*val (f32) ----------
__global__ __launch_bounds__(256) void k_compact(const float* __restrict__ Xin,
                                                 float* __restrict__ Xout,
                                                 const int* __restrict__ mp,
                                                 const float* __restrict__ score,
                                                 int* __restrict__ maxbuf, float* __restrict__ sumbuf,
                                                 int n) {
  __shared__ float smx[128], ssm[128];
  int b = blockIdx.x & 7;
  int base = (blockIdx.x >> 3) * 64;
  if (base >= n) return;
  int c = threadIdx.x & 127, h = threadIdx.x >> 7;
  float mx = -INFINITY, sm = 0.f;
  for (int r = h; r < 64; r += 2) {
    int node = base + r;
    if (node >= n) break;
    int m = mp[b * N0 + node];
    if (m < 0) continue;
    float val = score[b * N0 + node];
    float v = Xin[((size_t)b * N0 + node) * NC + c] * val;
    Xout[((size_t)b * N0 + m) * NC + c] = v;
    mx = fmaxf(mx, v);
    sm += v;
  }
  if (h) { smx[c] = mx; ssm[c] = sm; }
  __syncthreads();
  if (!h) {
    mx = fmaxf(mx, smx[c]);
    sm += ssm[c];
    atomicMax(&maxbuf[b * NC + c], f2ikey(mx));
    atomicAdd(&sumbuf[b * NC + c], sm);
  }
}

// ---------- remap edges in place; count next-depth in-degrees ----------
__global__ void k_remap(int* __restrict__ srcw, int* __restrict__ dstw,
                        const int* __restrict__ mp, int* __restrict__ cnt) {
  int tot = NB * NE;
  int tid = blockIdx.x * blockDim.x + threadIdx.x;
  int stride = gridDim.x * blockDim.x;
  for (int i = tid; i < tot; i += stride) {
    int d = dstw[i];
    if (d < 0) continue;
    int b = i / NE;
    int s = srcw[i];
    int ns = mp[b * N0 + s], nd = mp[b * N0 + d];
    if (ns >= 0 && nd >= 0) {
      srcw[i] = ns;
      dstw[i] = nd;
      atomicAdd(&cnt[b * N0 + nd], 1);
    } else {
      srcw[i] = 0;
      dstw[i] = -1;
    }
  }
}

// ---------- predictor MLP (folds readout-sum across depths) ----------
__global__ __launch_bounds__(256) void k_pred(const int* __restrict__ maxbuf,
                                              const float* __restrict__ sumbuf,
                                              const float* __restrict__ q1w, const float* __restrict__ q1b,
                                              const float* __restrict__ q2w, const float* __restrict__ q2b,
                                              const float* __restrict__ q3w, const float* __restrict__ q3b,
                                              float* __restrict__ out) {
  __shared__ float rr[256], h1[128], h2[64];
  int b = blockIdx.x, t = threadIdx.x;
  const float kdiv[4] = {13108.f, 10487.f, 8390.f, 6712.f};
  float acc = 0.f;
#pragma unroll
  for (int d = 0; d < 4; d++) {
    if (t < 128) acc += ikey2f(maxbuf[d * NB * NC + b * NC + t]);
    else acc += sumbuf[d * NB * NC + b * NC + (t - 128)] / kdiv[d];
  }
  rr[t] = acc;
  __syncthreads();
  if (t < 128) {
    float s = q1b[t];
    for (int j = 0; j < 256; j++) s = fmaf(rr[j], q1w[j * 128 + t], s);
    h1[t] = fmaxf(s, 0.f);
  }
  __syncthreads();
  if (t < 64) {
    float s = q2b[t];
    for (int j = 0; j < 128; j++) s = fmaf(h1[j], q2w[j * 64 + t], s);
    h2[t] = fmaxf(s, 0.f);
  }
  __syncthreads();
  if (t < 2) {
    float s = q3b[t];
    for (int j = 0; j < 64; j++) s = fmaf(h2[j], q3w[j * 2 + t], s);
    out[b * 2 + t] = s;
  }
}

// ---------- host orchestration ----------
extern "C" void kernel_launch(void* const* d_in, const int* in_sizes, int n_in,
                              void* d_out, int out_size, void* d_ws, size_t ws_size,
                              hipStream_t stream) {
  const float* x = (const float*)d_in[0];
  const int* src = (const int*)d_in[1];
  const int* dst = (const int*)d_in[2];
  const float* q1w = (const float*)d_in[23];
  const float* q1b = (const float*)d_in[24];
  const float* q2w = (const float*)d_in[25];
  const float* q2b = (const float*)d_in[26];
  const float* q3w = (const float*)d_in[27];
  const float* q3b = (const float*)d_in[28];

  char* p = (char*)d_ws;
  auto alloc = [&](size_t bytes) {
    char* q = p;
    p += (bytes + 255) & ~(size_t)255;
    return q;
  };
  float* Xa = (float*)alloc((size_t)NB * N0 * NC * 4);       // pooled x (f32)
  float* Xb = (float*)alloc((size_t)NB * N0 * NC * 4);       // x2 (f32, gin out)
  ushort_t* Xh = (ushort_t*)alloc((size_t)NB * N0 * NC * 2); // h0 (bf16)
  int* srcw = (int*)alloc((size_t)NB * NE * 4);
  int* dstw = (int*)alloc((size_t)NB * NE * 4);
  int* elist = (int*)alloc((size_t)NB * NE * 4);
  int* cnt = (int*)alloc((size_t)NB * N0 * 4);
  int* offs = (int*)alloc((size_t)NB * N0 * 4);
  int* cursor = (int*)alloc((size_t)NB * N0 * 4);
  float* score = (float*)alloc((size_t)NB * N0 * 4);
  int* mp = (int*)alloc((size_t)NB * N0 * 4);
  unsigned* vstar = (unsigned*)alloc(256);
  int* quota = (int*)alloc(256);
  int* gcnt = (int*)alloc(NB * 16 * 4);
  int* tcnt = (int*)alloc(NB * 16 * 4);
  int* maxbuf = (int*)alloc(4 * NB * NC * 4);
  float* sumbuf = (float*)alloc(4 * NB * NC * 4);
  ushort_t* Wt_all = (ushort_t*)alloc((size_t)8 * NC * NC * 2);

  hipMemsetAsync(cnt, 0, (size_t)NB * N0 * 4, stream);
  k_init<<<2048, 256, 0, stream>>>(src, dst, srcw, dstw, cnt, maxbuf, sumbuf);
  for (int i = 0; i < 4; i++) {
    k_wprep<<<64, 256, 0, stream>>>((const float*)d_in[3 + i * 5 + 0], Wt_all + (size_t)(2 * i) * NC * NC);
    k_wprep<<<64, 256, 0, stream>>>((const float*)d_in[3 + i * 5 + 2], Wt_all + (size_t)(2 * i + 1) * NC * NC);
  }

  static const int NSv[4] = {16384, 13108, 10487, 8390};
  static const int KSv[4] = {13108, 10487, 8390, 6712};
  for (int i = 0; i < 4; i++) {
    int n = NSv[i], k = KSv[i];
    const float* b1 = (const float*)d_in[3 + i * 5 + 1];
    const float* b2 = (const float*)d_in[3 + i * 5 + 3];
    const float* pw = (const float*)d_in[3 + i * 5 + 4];
    const ushort_t* w1t = Wt_all + (size_t)(2 * i) * NC * NC;
    const ushort_t* w2t = Wt_all + (size_t)(2 * i + 1) * NC * NC;
    const float* cur = (i == 0) ? x : Xa;

    k_scan<<<NB, 1024, 0, stream>>>(cnt, offs, cursor);
    k_fill<<<1024, 256, 0, stream>>>(srcw, dstw, cursor, elist);

    k_gather<<<((n + 3) / 4) * 8, 256, 0, stream>>>(cur, Xh, offs, cursor, elist, n);

    k_gin<<<((n + 127) / 128) * 8, 256, 0, stream>>>(Xh, Xb, w1t, b1, w2t, b2, pw, score, n);

    k_select<<<NB, 1024, 0, stream>>>(score, vstar, quota, gcnt, tcnt, n, k);
    dim3 gm(16, NB);
    k_map_wr<<<gm, 1024, 0, stream>>>(score, vstar, quota, gcnt, tcnt, mp, n);

    k_compact<<<((n + 63) / 64) * 8, 256, 0, stream>>>(Xb, Xa, mp, score,
                                                       maxbuf + i * NB * NC, sumbuf + i * NB * NC, n);
    k_remap<<<1024, 256, 0, stream>>>(srcw, dstw, mp, cnt);
  }

  k_pred<<<NB, 256, 0, stream>>>(maxbuf, sumbuf, q1w, q1b, q2w, q2b, q3w, q3b, (float*)d_out);
}